// Round 1
// baseline (555.355 us; speedup 1.0000x reference)
//
#include <hip/hip_runtime.h>
#include <hip/hip_bf16.h>

static __device__ __forceinline__ float relu_f(float v) { return v > 0.f ? v : 0.f; }

// ---------------- CSR build ----------------

__global__ void init_kernel(float* __restrict__ deg, int* __restrict__ indeg, int n) {
  int i = blockIdx.x * blockDim.x + threadIdx.x;
  if (i < n) { deg[i] = 1.0f; indeg[i] = 0; }  // 1.0 = self-loop weight
}

__global__ void edge_count_kernel(const int* __restrict__ dst, const float* __restrict__ ew,
                                  float* __restrict__ deg, int* __restrict__ indeg, int E) {
  int e = blockIdx.x * blockDim.x + threadIdx.x;
  if (e >= E) return;
  int d = dst[e];
  atomicAdd(&deg[d], ew[e]);
  atomicAdd(&indeg[d], 1);
}

__global__ void dinv_kernel(const float* __restrict__ deg, float* __restrict__ dinv, int n) {
  int i = blockIdx.x * blockDim.x + threadIdx.x;
  if (i < n) { float d = deg[i]; dinv[i] = (d > 0.f) ? rsqrtf(d) : 0.f; }
}

// single-block scan over indeg -> rowptr (inclusive at i+1), cursor = exclusive
__global__ __launch_bounds__(1024) void scan_kernel(const int* __restrict__ indeg,
                                                    int* __restrict__ rowptr,
                                                    int* __restrict__ cursor, int n) {
  int t = threadIdx.x;
  int per = (n + 1023) >> 10;
  int begin = t * per; if (begin > n) begin = n;
  int end = begin + per; if (end > n) end = n;
  int s = 0;
  for (int i = begin; i < end; ++i) s += indeg[i];
  int lane = t & 63, wid = t >> 6;
  int v = s;
  #pragma unroll
  for (int off = 1; off < 64; off <<= 1) {
    int u = __shfl_up(v, off, 64);
    if (lane >= off) v += u;
  }
  __shared__ int wtot[16], woff[16];
  if (lane == 63) wtot[wid] = v;
  __syncthreads();
  if (t < 16) {
    int o = 0;
    for (int j = 0; j < t; ++j) o += wtot[j];
    woff[t] = o;
  }
  __syncthreads();
  int run = woff[wid] + (v - s);  // exclusive prefix for this thread's chunk
  for (int i = begin; i < end; ++i) {
    int val = indeg[i];
    cursor[i] = run;
    run += val;
    rowptr[i + 1] = run;
  }
  if (t == 0) rowptr[0] = 0;
}

__global__ void edge_fill_kernel(const int* __restrict__ src, const int* __restrict__ dst,
                                 const float* __restrict__ ew, const float* __restrict__ dinv,
                                 int* __restrict__ cursor, int2* __restrict__ epack, int E) {
  int e = blockIdx.x * blockDim.x + threadIdx.x;
  if (e >= E) return;
  int sN = src[e], d = dst[e];
  int p = atomicAdd(&cursor[d], 1);
  float w = dinv[sN] * ew[e] * dinv[d];
  epack[p] = make_int2(sN, __float_as_int(w));
}

// ---------------- aggregation: one wave per node ----------------

__global__ __launch_bounds__(256) void aggregate_kernel(const float2* __restrict__ x2,
    const float* __restrict__ dinv, const int* __restrict__ rowptr,
    const int2* __restrict__ epack, float2* __restrict__ agg2, int n) {
  int gid = blockIdx.x * blockDim.x + threadIdx.x;
  int node = gid >> 6;
  int lane = gid & 63;
  if (node >= n) return;
  float di = dinv[node];
  float2 xv = x2[node * 64 + lane];
  float sw = di * di;  // self-loop norm: dinv*1*dinv
  float2 acc = make_float2(sw * xv.x, sw * xv.y);
  int s = rowptr[node], e = rowptr[node + 1];
  for (int j = s; j < e; ++j) {
    int2 pk = epack[j];
    float w = __int_as_float(pk.y);
    float2 xc = x2[(size_t)pk.x * 64 + lane];
    acc.x += w * xc.x;
    acc.y += w * xc.y;
  }
  agg2[node * 64 + lane] = acc;
}

// ---------------- GEMM (agg @ W + b, ReLU), f32, 32 rows/block ----------------
// h4 may alias agg4: the whole 32-row tile is staged into LDS before any write,
// and each row belongs to exactly one block.

__global__ __launch_bounds__(256) void gemm_relu_kernel(const float4* __restrict__ agg4,
    const float* __restrict__ W, const float* __restrict__ bias,
    float4* __restrict__ h4, int n) {
  __shared__ float sA[32 * 128];   // 16 KB
  __shared__ float sW[64 * 128];   // 32 KB (two K-chunks)
  int tid = threadIdx.x;
  int row0 = blockIdx.x * 32;
  int nb = n - row0; if (nb > 32) nb = 32;
  float4* sA4 = (float4*)sA;
  for (int idx = tid; idx < 32 * 32; idx += 256) {
    int r = idx >> 5;
    sA4[idx] = (r < nb) ? agg4[(size_t)row0 * 32 + idx] : make_float4(0.f, 0.f, 0.f, 0.f);
  }
  int tx = tid & 31, ty = tid >> 5;   // cols 4*tx..+3, rows 4*ty..+3
  float acc[4][4] = {};
  const float4* W4 = (const float4*)W;
  float4* sW4 = (float4*)sW;
  for (int kk = 0; kk < 128; kk += 64) {
    __syncthreads();
    for (int idx = tid; idx < 64 * 32; idx += 256)
      sW4[idx] = W4[kk * 32 + idx];
    __syncthreads();
    #pragma unroll 8
    for (int k = 0; k < 64; ++k) {
      float a0 = sA[(4 * ty + 0) * 128 + kk + k];
      float a1 = sA[(4 * ty + 1) * 128 + kk + k];
      float a2 = sA[(4 * ty + 2) * 128 + kk + k];
      float a3 = sA[(4 * ty + 3) * 128 + kk + k];
      float4 wv = *(const float4*)&sW[k * 128 + 4 * tx];
      acc[0][0] += a0 * wv.x; acc[0][1] += a0 * wv.y; acc[0][2] += a0 * wv.z; acc[0][3] += a0 * wv.w;
      acc[1][0] += a1 * wv.x; acc[1][1] += a1 * wv.y; acc[1][2] += a1 * wv.z; acc[1][3] += a1 * wv.w;
      acc[2][0] += a2 * wv.x; acc[2][1] += a2 * wv.y; acc[2][2] += a2 * wv.z; acc[2][3] += a2 * wv.w;
      acc[3][0] += a3 * wv.x; acc[3][1] += a3 * wv.y; acc[3][2] += a3 * wv.z; acc[3][3] += a3 * wv.w;
    }
  }
  float4 bb = ((const float4*)bias)[tx];
  #pragma unroll
  for (int i = 0; i < 4; ++i) {
    int r = 4 * ty + i;
    if (r < nb) {
      float4 o;
      o.x = relu_f(acc[i][0] + bb.x);
      o.y = relu_f(acc[i][1] + bb.y);
      o.z = relu_f(acc[i][2] + bb.z);
      o.w = relu_f(acc[i][3] + bb.w);
      h4[(size_t)(row0 + r) * 32 + tx] = o;
    }
  }
}

// ---------------- pooling: one block per graph (batch sorted) ----------------

__global__ __launch_bounds__(128) void pool_kernel(const float* __restrict__ h,
    const int* __restrict__ batch, const float* __restrict__ rho,
    float* __restrict__ hg, int n) {
  int g = blockIdx.x;
  int c = threadIdx.x;
  int lo = 0, hi = n;
  while (lo < hi) { int mid = (lo + hi) >> 1; if (batch[mid] < g) lo = mid + 1; else hi = mid; }
  int s = lo;
  hi = n;
  while (lo < hi) { int mid = (lo + hi) >> 1; if (batch[mid] < g + 1) lo = mid + 1; else hi = mid; }
  int e = lo;
  float mx = 0.f, sum = 0.f;  // h >= 0 after ReLU, and empty graph -> 0 (matches ref)
  for (int i = s; i < e; ++i) {
    float v = h[(size_t)i * 128 + c];
    mx = fmaxf(mx, v);
    sum += v;
  }
  float cnt = (float)(e - s);
  hg[g * 257 + c] = mx;
  hg[g * 257 + 128 + c] = sum / fmaxf(cnt, 1.f);
  if (c == 0) hg[g * 257 + 256] = rho[g];
}

// ---------------- MLP: one block per graph row ----------------

__global__ __launch_bounds__(128) void mlp_kernel(const float* __restrict__ hg,
    const float* __restrict__ w1, const float* __restrict__ b1,
    const float* __restrict__ w2, const float* __restrict__ b2,
    const float* __restrict__ w3, const float* __restrict__ b3,
    float* __restrict__ out) {
  __shared__ float s_in[257];
  __shared__ float s_z1[128];
  __shared__ float s_z2[128];
  int g = blockIdx.x, t = threadIdx.x;
  for (int i = t; i < 257; i += 128) s_in[i] = hg[g * 257 + i];
  __syncthreads();
  float s = b1[t];
  for (int k = 0; k < 257; ++k) s += s_in[k] * w1[k * 128 + t];
  s_z1[t] = relu_f(s);
  __syncthreads();
  s = b2[t];
  for (int k = 0; k < 128; ++k) s += s_z1[k] * w2[k * 128 + t];
  s_z2[t] = relu_f(s);
  __syncthreads();
  if (t < 36) {
    s = b3[t];
    for (int k = 0; k < 128; ++k) s += s_z2[k] * w3[k * 36 + t];
    out[g * 36 + t] = s;
  }
}

// ---------------- launch ----------------

extern "C" void kernel_launch(void* const* d_in, const int* in_sizes, int n_in,
                              void* d_out, int out_size, void* d_ws, size_t ws_size,
                              hipStream_t stream) {
  const float* x      = (const float*)d_in[0];
  const float* ew     = (const float*)d_in[1];
  const float* rho    = (const float*)d_in[2];
  const float* conv_w = (const float*)d_in[3];
  const float* conv_b = (const float*)d_in[4];
  const float* w1 = (const float*)d_in[5];
  const float* b1 = (const float*)d_in[6];
  const float* w2 = (const float*)d_in[7];
  const float* b2 = (const float*)d_in[8];
  const float* w3 = (const float*)d_in[9];
  const float* b3 = (const float*)d_in[10];
  const int* eidx  = (const int*)d_in[11];
  const int* batch = (const int*)d_in[12];

  const int N = in_sizes[0] / 128;
  const int E = in_sizes[1];
  const int G = in_sizes[2];
  const int* srcp = eidx;
  const int* dstp = eidx + E;

  char* p = (char*)d_ws;
  auto carve = [&](size_t bytes) { char* r = p; p += (bytes + 255) & ~(size_t)255; return (void*)r; };
  float* deg    = (float*)carve((size_t)N * 4);
  float* dinv   = (float*)carve((size_t)N * 4);
  int*   indeg  = (int*)  carve((size_t)N * 4);
  int*   rowptr = (int*)  carve((size_t)(N + 1) * 4);
  int*   cursor = (int*)  carve((size_t)(N + 1) * 4);
  int2*  epack  = (int2*) carve((size_t)E * 8);
  float* agg    = (float*)carve((size_t)N * 128 * 4);  // reused in-place as h
  float* hg     = (float*)carve((size_t)G * 257 * 4);

  init_kernel<<<(N + 255) / 256, 256, 0, stream>>>(deg, indeg, N);
  edge_count_kernel<<<(E + 255) / 256, 256, 0, stream>>>(dstp, ew, deg, indeg, E);
  dinv_kernel<<<(N + 255) / 256, 256, 0, stream>>>(deg, dinv, N);
  scan_kernel<<<1, 1024, 0, stream>>>(indeg, rowptr, cursor, N);
  edge_fill_kernel<<<(E + 255) / 256, 256, 0, stream>>>(srcp, dstp, ew, dinv, cursor, epack, E);
  aggregate_kernel<<<(N + 3) / 4, 256, 0, stream>>>((const float2*)x, dinv, rowptr, epack,
                                                    (float2*)agg, N);
  gemm_relu_kernel<<<(N + 31) / 32, 256, 0, stream>>>((const float4*)agg, conv_w, conv_b,
                                                      (float4*)agg, N);
  pool_kernel<<<G, 128, 0, stream>>>(agg, batch, rho, hg, N);
  mlp_kernel<<<G, 128, 0, stream>>>(hg, w1, b1, w2, b2, w3, b3, (float*)d_out);
}

// Round 2
// 402.121 us; speedup vs baseline: 1.3811x; 1.3811x over previous
//
#include <hip/hip_runtime.h>
#include <hip/hip_bf16.h>

static __device__ __forceinline__ float relu_f(float v) { return v > 0.f ? v : 0.f; }

// ---------------- CSR build ----------------

__global__ void init_kernel(float* __restrict__ deg, int* __restrict__ indeg,
                            float* __restrict__ gmax, float* __restrict__ gsum,
                            float* __restrict__ gcnt, int n, int gch) {
  int i = blockIdx.x * blockDim.x + threadIdx.x;
  if (i < n) { deg[i] = 1.0f; indeg[i] = 0; }  // 1.0 = self-loop weight
  if (i < gch) { gmax[i] = 0.f; gsum[i] = 0.f; }
  if (i < (gch >> 7)) gcnt[i] = 0.f;
}

__global__ void edge_count_kernel(const int* __restrict__ dst, const float* __restrict__ ew,
                                  float* __restrict__ deg, int* __restrict__ indeg, int E) {
  int e = blockIdx.x * blockDim.x + threadIdx.x;
  if (e >= E) return;
  int d = dst[e];
  atomicAdd(&deg[d], ew[e]);
  atomicAdd(&indeg[d], 1);
}

__global__ void dinv_kernel(const float* __restrict__ deg, float* __restrict__ dinv, int n) {
  int i = blockIdx.x * blockDim.x + threadIdx.x;
  if (i < n) { float d = deg[i]; dinv[i] = (d > 0.f) ? rsqrtf(d) : 0.f; }
}

// single-block scan over indeg -> rowptr (inclusive at i+1), cursor = exclusive
__global__ __launch_bounds__(1024) void scan_kernel(const int* __restrict__ indeg,
                                                    int* __restrict__ rowptr,
                                                    int* __restrict__ cursor, int n) {
  int t = threadIdx.x;
  int per = (n + 1023) >> 10;
  int begin = t * per; if (begin > n) begin = n;
  int end = begin + per; if (end > n) end = n;
  int s = 0;
  for (int i = begin; i < end; ++i) s += indeg[i];
  int lane = t & 63, wid = t >> 6;
  int v = s;
  #pragma unroll
  for (int off = 1; off < 64; off <<= 1) {
    int u = __shfl_up(v, off, 64);
    if (lane >= off) v += u;
  }
  __shared__ int wtot[16], woff[16];
  if (lane == 63) wtot[wid] = v;
  __syncthreads();
  if (t < 16) {
    int o = 0;
    for (int j = 0; j < t; ++j) o += wtot[j];
    woff[t] = o;
  }
  __syncthreads();
  int run = woff[wid] + (v - s);  // exclusive prefix for this thread's chunk
  for (int i = begin; i < end; ++i) {
    int val = indeg[i];
    cursor[i] = run;
    run += val;
    rowptr[i + 1] = run;
  }
  if (t == 0) rowptr[0] = 0;
}

__global__ void edge_fill_kernel(const int* __restrict__ src, const int* __restrict__ dst,
                                 const float* __restrict__ ew, const float* __restrict__ dinv,
                                 int* __restrict__ cursor, int2* __restrict__ epack, int E) {
  int e = blockIdx.x * blockDim.x + threadIdx.x;
  if (e >= E) return;
  int sN = src[e], d = dst[e];
  int p = atomicAdd(&cursor[d], 1);
  float w = dinv[sN] * ew[e] * dinv[d];
  epack[p] = make_int2(sN, __float_as_int(w));
}

// ---------------- aggregation: one wave per node ----------------

__global__ __launch_bounds__(256) void aggregate_kernel(const float2* __restrict__ x2,
    const float* __restrict__ dinv, const int* __restrict__ rowptr,
    const int2* __restrict__ epack, float2* __restrict__ agg2, int n) {
  int gid = blockIdx.x * blockDim.x + threadIdx.x;
  int node = gid >> 6;
  int lane = gid & 63;
  if (node >= n) return;
  float di = dinv[node];
  float2 xv = x2[node * 64 + lane];
  float sw = di * di;  // self-loop norm: dinv*1*dinv
  float2 acc = make_float2(sw * xv.x, sw * xv.y);
  int s = rowptr[node], e = rowptr[node + 1];
  for (int j = s; j < e; ++j) {
    int2 pk = epack[j];
    float w = __int_as_float(pk.y);
    float2 xc = x2[(size_t)pk.x * 64 + lane];
    acc.x += w * xc.x;
    acc.y += w * xc.y;
  }
  agg2[node * 64 + lane] = acc;
}

// ---------------- GEMM (agg @ W + b, ReLU), f32, 32 rows/block ----------------
// h4 may alias agg4: the whole 32-row tile is staged into LDS before any write,
// and each row belongs to exactly one block.

__global__ __launch_bounds__(256) void gemm_relu_kernel(const float4* __restrict__ agg4,
    const float* __restrict__ W, const float* __restrict__ bias,
    float4* __restrict__ h4, int n) {
  __shared__ float sA[32 * 128];   // 16 KB
  __shared__ float sW[64 * 128];   // 32 KB (two K-chunks)
  int tid = threadIdx.x;
  int row0 = blockIdx.x * 32;
  int nb = n - row0; if (nb > 32) nb = 32;
  float4* sA4 = (float4*)sA;
  for (int idx = tid; idx < 32 * 32; idx += 256) {
    int r = idx >> 5;
    sA4[idx] = (r < nb) ? agg4[(size_t)row0 * 32 + idx] : make_float4(0.f, 0.f, 0.f, 0.f);
  }
  int tx = tid & 31, ty = tid >> 5;   // cols 4*tx..+3, rows 4*ty..+3
  float acc[4][4] = {};
  const float4* W4 = (const float4*)W;
  float4* sW4 = (float4*)sW;
  for (int kk = 0; kk < 128; kk += 64) {
    __syncthreads();
    for (int idx = tid; idx < 64 * 32; idx += 256)
      sW4[idx] = W4[kk * 32 + idx];
    __syncthreads();
    #pragma unroll 8
    for (int k = 0; k < 64; ++k) {
      float a0 = sA[(4 * ty + 0) * 128 + kk + k];
      float a1 = sA[(4 * ty + 1) * 128 + kk + k];
      float a2 = sA[(4 * ty + 2) * 128 + kk + k];
      float a3 = sA[(4 * ty + 3) * 128 + kk + k];
      float4 wv = *(const float4*)&sW[k * 128 + 4 * tx];
      acc[0][0] += a0 * wv.x; acc[0][1] += a0 * wv.y; acc[0][2] += a0 * wv.z; acc[0][3] += a0 * wv.w;
      acc[1][0] += a1 * wv.x; acc[1][1] += a1 * wv.y; acc[1][2] += a1 * wv.z; acc[1][3] += a1 * wv.w;
      acc[2][0] += a2 * wv.x; acc[2][1] += a2 * wv.y; acc[2][2] += a2 * wv.z; acc[2][3] += a2 * wv.w;
      acc[3][0] += a3 * wv.x; acc[3][1] += a3 * wv.y; acc[3][2] += a3 * wv.z; acc[3][3] += a3 * wv.w;
    }
  }
  float4 bb = ((const float4*)bias)[tx];
  #pragma unroll
  for (int i = 0; i < 4; ++i) {
    int r = 4 * ty + i;
    if (r < nb) {
      float4 o;
      o.x = relu_f(acc[i][0] + bb.x);
      o.y = relu_f(acc[i][1] + bb.y);
      o.z = relu_f(acc[i][2] + bb.z);
      o.w = relu_f(acc[i][3] + bb.w);
      h4[(size_t)(row0 + r) * 32 + tx] = o;
    }
  }
}

// ---------------- pooling: node-parallel partial reduce + atomic flush ----------------
// batch is sorted; a 64-node chunk spans few graphs. Accumulate per-segment
// max/sum in registers, flush once per segment boundary. h >= 0 post-ReLU, so
// atomicMax on the int bit pattern is order-correct (gmax initialized to 0).

#define POOL_CHUNK 64

__global__ __launch_bounds__(128) void pool_kernel(const float* __restrict__ h,
    const int* __restrict__ batch, float* __restrict__ gmax, float* __restrict__ gsum,
    float* __restrict__ gcnt, int n) {
  int c = threadIdx.x;
  int n0 = blockIdx.x * POOL_CHUNK;
  if (n0 >= n) return;
  int n1 = n0 + POOL_CHUNK; if (n1 > n) n1 = n;
  float mx = 0.f, sm = 0.f;
  int cnt = 0;
  int cur = batch[n0];
  for (int i = n0; i < n1; ++i) {
    int g = batch[i];
    if (g != cur) {
      atomicMax((int*)&gmax[cur * 128 + c], __float_as_int(mx));
      atomicAdd(&gsum[cur * 128 + c], sm);
      if (c == 0) atomicAdd(&gcnt[cur], (float)cnt);
      mx = 0.f; sm = 0.f; cnt = 0; cur = g;
    }
    float v = h[(size_t)i * 128 + c];
    mx = fmaxf(mx, v);
    sm += v;
    ++cnt;
  }
  atomicMax((int*)&gmax[cur * 128 + c], __float_as_int(mx));
  atomicAdd(&gsum[cur * 128 + c], sm);
  if (c == 0) atomicAdd(&gcnt[cur], (float)cnt);
}

// ---------------- MLP: one block per graph row (reads pooled buffers directly) ----------------

__global__ __launch_bounds__(128) void mlp_kernel(const float* __restrict__ gmax,
    const float* __restrict__ gsum, const float* __restrict__ gcnt,
    const float* __restrict__ rho,
    const float* __restrict__ w1, const float* __restrict__ b1,
    const float* __restrict__ w2, const float* __restrict__ b2,
    const float* __restrict__ w3, const float* __restrict__ b3,
    float* __restrict__ out) {
  __shared__ float s_in[257];
  __shared__ float s_z1[128];
  __shared__ float s_z2[128];
  int g = blockIdx.x, t = threadIdx.x;
  float inv_cnt = 1.f / fmaxf(gcnt[g], 1.f);
  s_in[t] = gmax[g * 128 + t];
  s_in[128 + t] = gsum[g * 128 + t] * inv_cnt;
  if (t == 0) s_in[256] = rho[g];
  __syncthreads();
  float s = b1[t];
  for (int k = 0; k < 257; ++k) s += s_in[k] * w1[k * 128 + t];
  s_z1[t] = relu_f(s);
  __syncthreads();
  s = b2[t];
  for (int k = 0; k < 128; ++k) s += s_z1[k] * w2[k * 128 + t];
  s_z2[t] = relu_f(s);
  __syncthreads();
  if (t < 36) {
    s = b3[t];
    for (int k = 0; k < 128; ++k) s += s_z2[k] * w3[k * 36 + t];
    out[g * 36 + t] = s;
  }
}

// ---------------- launch ----------------

extern "C" void kernel_launch(void* const* d_in, const int* in_sizes, int n_in,
                              void* d_out, int out_size, void* d_ws, size_t ws_size,
                              hipStream_t stream) {
  const float* x      = (const float*)d_in[0];
  const float* ew     = (const float*)d_in[1];
  const float* rho    = (const float*)d_in[2];
  const float* conv_w = (const float*)d_in[3];
  const float* conv_b = (const float*)d_in[4];
  const float* w1 = (const float*)d_in[5];
  const float* b1 = (const float*)d_in[6];
  const float* w2 = (const float*)d_in[7];
  const float* b2 = (const float*)d_in[8];
  const float* w3 = (const float*)d_in[9];
  const float* b3 = (const float*)d_in[10];
  const int* eidx  = (const int*)d_in[11];
  const int* batch = (const int*)d_in[12];

  const int N = in_sizes[0] / 128;
  const int E = in_sizes[1];
  const int G = in_sizes[2];
  const int* srcp = eidx;
  const int* dstp = eidx + E;

  char* p = (char*)d_ws;
  auto carve = [&](size_t bytes) { char* r = p; p += (bytes + 255) & ~(size_t)255; return (void*)r; };
  float* deg    = (float*)carve((size_t)N * 4);
  float* dinv   = (float*)carve((size_t)N * 4);
  int*   indeg  = (int*)  carve((size_t)N * 4);
  int*   rowptr = (int*)  carve((size_t)(N + 1) * 4);
  int*   cursor = (int*)  carve((size_t)(N + 1) * 4);
  int2*  epack  = (int2*) carve((size_t)E * 8);
  float* agg    = (float*)carve((size_t)N * 128 * 4);  // reused in-place as h
  float* gmax   = (float*)carve((size_t)G * 128 * 4);
  float* gsum   = (float*)carve((size_t)G * 128 * 4);
  float* gcnt   = (float*)carve((size_t)G * 4);

  init_kernel<<<(N + 255) / 256, 256, 0, stream>>>(deg, indeg, gmax, gsum, gcnt, N, G * 128);
  edge_count_kernel<<<(E + 255) / 256, 256, 0, stream>>>(dstp, ew, deg, indeg, E);
  dinv_kernel<<<(N + 255) / 256, 256, 0, stream>>>(deg, dinv, N);
  scan_kernel<<<1, 1024, 0, stream>>>(indeg, rowptr, cursor, N);
  edge_fill_kernel<<<(E + 255) / 256, 256, 0, stream>>>(srcp, dstp, ew, dinv, cursor, epack, E);
  aggregate_kernel<<<(N + 3) / 4, 256, 0, stream>>>((const float2*)x, dinv, rowptr, epack,
                                                    (float2*)agg, N);
  gemm_relu_kernel<<<(N + 31) / 32, 256, 0, stream>>>((const float4*)agg, conv_w, conv_b,
                                                      (float4*)agg, N);
  pool_kernel<<<(N + POOL_CHUNK - 1) / POOL_CHUNK, 128, 0, stream>>>(agg, batch, gmax, gsum,
                                                                     gcnt, N);
  mlp_kernel<<<G, 128, 0, stream>>>(gmax, gsum, gcnt, rho, w1, b1, w2, b2, w3, b3,
                                    (float*)d_out);
}

// Round 3
// 323.374 us; speedup vs baseline: 1.7174x; 1.2435x over previous
//
#include <hip/hip_runtime.h>
#include <hip/hip_bf16.h>

static __device__ __forceinline__ float relu_f(float v) { return v > 0.f ? v : 0.f; }

// ---------------- CSR build ----------------

__global__ void init_kernel(float* __restrict__ deg, int* __restrict__ indeg,
                            float* __restrict__ gmax, float* __restrict__ gsum,
                            float* __restrict__ gcnt, int n, int gch) {
  int i = blockIdx.x * blockDim.x + threadIdx.x;
  if (i < n) { deg[i] = 1.0f; indeg[i] = 0; }  // 1.0 = self-loop weight
  if (i < gch) { gmax[i] = 0.f; gsum[i] = 0.f; }
  if (i < (gch >> 7)) gcnt[i] = 0.f;
}

__global__ void edge_count_kernel(const int* __restrict__ dst, const float* __restrict__ ew,
                                  float* __restrict__ deg, int* __restrict__ indeg, int E) {
  int e = blockIdx.x * blockDim.x + threadIdx.x;
  if (e >= E) return;
  int d = dst[e];
  atomicAdd(&deg[d], ew[e]);
  atomicAdd(&indeg[d], 1);
}

__global__ void dinv_kernel(const float* __restrict__ deg, float* __restrict__ dinv, int n) {
  int i = blockIdx.x * blockDim.x + threadIdx.x;
  if (i < n) { float d = deg[i]; dinv[i] = (d > 0.f) ? rsqrtf(d) : 0.f; }
}

// ---------------- device-wide exclusive scan of indeg (3 kernels) ----------------

__global__ __launch_bounds__(1024) void scan_reduce_kernel(const int* __restrict__ indeg,
                                                           int* __restrict__ bsum, int n) {
  int i = blockIdx.x * 1024 + threadIdx.x;
  int v = (i < n) ? indeg[i] : 0;
  #pragma unroll
  for (int off = 32; off; off >>= 1) v += __shfl_down(v, off, 64);
  __shared__ int ws[16];
  int lane = threadIdx.x & 63, wid = threadIdx.x >> 6;
  if (lane == 0) ws[wid] = v;
  __syncthreads();
  if (threadIdx.x == 0) {
    int s = 0;
    #pragma unroll
    for (int j = 0; j < 16; ++j) s += ws[j];
    bsum[blockIdx.x] = s;
  }
}

// single block: exclusive scan of bsum[nb], nb <= 1024
__global__ __launch_bounds__(1024) void scan_bsum_kernel(int* __restrict__ bsum, int nb) {
  int t = threadIdx.x;
  int v = (t < nb) ? bsum[t] : 0;
  int lane = t & 63, wid = t >> 6;
  int inc = v;
  #pragma unroll
  for (int off = 1; off < 64; off <<= 1) {
    int u = __shfl_up(inc, off, 64);
    if (lane >= off) inc += u;
  }
  __shared__ int wtot[16];
  if (lane == 63) wtot[wid] = inc;
  __syncthreads();
  int woff = 0;
  for (int j = 0; j < wid; ++j) woff += wtot[j];
  if (t < nb) bsum[t] = woff + inc - v;  // exclusive
}

__global__ __launch_bounds__(1024) void scan_write_kernel(const int* __restrict__ indeg,
    const int* __restrict__ bsum, int* __restrict__ rowptr, int* __restrict__ cursor, int n) {
  int i = blockIdx.x * 1024 + threadIdx.x;
  int v = (i < n) ? indeg[i] : 0;
  int lane = threadIdx.x & 63, wid = threadIdx.x >> 6;
  int inc = v;
  #pragma unroll
  for (int off = 1; off < 64; off <<= 1) {
    int u = __shfl_up(inc, off, 64);
    if (lane >= off) inc += u;
  }
  __shared__ int wtot[16];
  if (lane == 63) wtot[wid] = inc;
  __syncthreads();
  int woff = 0;
  for (int j = 0; j < wid; ++j) woff += wtot[j];
  int excl = bsum[blockIdx.x] + woff + inc - v;
  if (i < n) {
    cursor[i] = excl;
    rowptr[i + 1] = excl + v;
    if (i == 0) rowptr[0] = 0;
  }
}

__global__ void edge_fill_kernel(const int* __restrict__ src, const int* __restrict__ dst,
                                 const float* __restrict__ ew, const float* __restrict__ dinv,
                                 int* __restrict__ cursor, int2* __restrict__ epack, int E) {
  int e = blockIdx.x * blockDim.x + threadIdx.x;
  if (e >= E) return;
  int sN = src[e], d = dst[e];
  int p = atomicAdd(&cursor[d], 1);
  float w = dinv[sN] * ew[e] * dinv[d];
  epack[p] = make_int2(sN, __float_as_int(w));
}

// ---------------- aggregation: one wave per node ----------------

__global__ __launch_bounds__(256) void aggregate_kernel(const float2* __restrict__ x2,
    const float* __restrict__ dinv, const int* __restrict__ rowptr,
    const int2* __restrict__ epack, float2* __restrict__ agg2, int n) {
  int gid = blockIdx.x * blockDim.x + threadIdx.x;
  int node = gid >> 6;
  int lane = gid & 63;
  if (node >= n) return;
  float di = dinv[node];
  float2 xv = x2[node * 64 + lane];
  float sw = di * di;  // self-loop norm: dinv*1*dinv
  float2 acc = make_float2(sw * xv.x, sw * xv.y);
  int s = rowptr[node], e = rowptr[node + 1];
  for (int j = s; j < e; ++j) {
    int2 pk = epack[j];
    float w = __int_as_float(pk.y);
    float2 xc = x2[(size_t)pk.x * 64 + lane];
    acc.x += w * xc.x;
    acc.y += w * xc.y;
  }
  agg2[node * 64 + lane] = acc;
}

// ---------------- GEMM (agg @ W + b, ReLU), f32, 32 rows/block ----------------
// h4 may alias agg4: the whole 32-row tile is staged into LDS before any write,
// and each row belongs to exactly one block.

__global__ __launch_bounds__(256) void gemm_relu_kernel(const float4* __restrict__ agg4,
    const float* __restrict__ W, const float* __restrict__ bias,
    float4* __restrict__ h4, int n) {
  __shared__ float sA[32 * 128];   // 16 KB
  __shared__ float sW[64 * 128];   // 32 KB (two K-chunks)
  int tid = threadIdx.x;
  int row0 = blockIdx.x * 32;
  int nb = n - row0; if (nb > 32) nb = 32;
  float4* sA4 = (float4*)sA;
  for (int idx = tid; idx < 32 * 32; idx += 256) {
    int r = idx >> 5;
    sA4[idx] = (r < nb) ? agg4[(size_t)row0 * 32 + idx] : make_float4(0.f, 0.f, 0.f, 0.f);
  }
  int tx = tid & 31, ty = tid >> 5;   // cols 4*tx..+3, rows 4*ty..+3
  float acc[4][4] = {};
  const float4* W4 = (const float4*)W;
  float4* sW4 = (float4*)sW;
  for (int kk = 0; kk < 128; kk += 64) {
    __syncthreads();
    for (int idx = tid; idx < 64 * 32; idx += 256)
      sW4[idx] = W4[kk * 32 + idx];
    __syncthreads();
    #pragma unroll 8
    for (int k = 0; k < 64; ++k) {
      float a0 = sA[(4 * ty + 0) * 128 + kk + k];
      float a1 = sA[(4 * ty + 1) * 128 + kk + k];
      float a2 = sA[(4 * ty + 2) * 128 + kk + k];
      float a3 = sA[(4 * ty + 3) * 128 + kk + k];
      float4 wv = *(const float4*)&sW[k * 128 + 4 * tx];
      acc[0][0] += a0 * wv.x; acc[0][1] += a0 * wv.y; acc[0][2] += a0 * wv.z; acc[0][3] += a0 * wv.w;
      acc[1][0] += a1 * wv.x; acc[1][1] += a1 * wv.y; acc[1][2] += a1 * wv.z; acc[1][3] += a1 * wv.w;
      acc[2][0] += a2 * wv.x; acc[2][1] += a2 * wv.y; acc[2][2] += a2 * wv.z; acc[2][3] += a2 * wv.w;
      acc[3][0] += a3 * wv.x; acc[3][1] += a3 * wv.y; acc[3][2] += a3 * wv.z; acc[3][3] += a3 * wv.w;
    }
  }
  float4 bb = ((const float4*)bias)[tx];
  #pragma unroll
  for (int i = 0; i < 4; ++i) {
    int r = 4 * ty + i;
    if (r < nb) {
      float4 o;
      o.x = relu_f(acc[i][0] + bb.x);
      o.y = relu_f(acc[i][1] + bb.y);
      o.z = relu_f(acc[i][2] + bb.z);
      o.w = relu_f(acc[i][3] + bb.w);
      h4[(size_t)(row0 + r) * 32 + tx] = o;
    }
  }
}

// ---------------- pooling: node-parallel partial reduce + atomic flush ----------------

#define POOL_CHUNK 64

__global__ __launch_bounds__(128) void pool_kernel(const float* __restrict__ h,
    const int* __restrict__ batch, float* __restrict__ gmax, float* __restrict__ gsum,
    float* __restrict__ gcnt, int n) {
  int c = threadIdx.x;
  int n0 = blockIdx.x * POOL_CHUNK;
  if (n0 >= n) return;
  int n1 = n0 + POOL_CHUNK; if (n1 > n) n1 = n;
  float mx = 0.f, sm = 0.f;
  int cnt = 0;
  int cur = batch[n0];
  for (int i = n0; i < n1; ++i) {
    int g = batch[i];
    if (g != cur) {
      atomicMax((int*)&gmax[cur * 128 + c], __float_as_int(mx));
      atomicAdd(&gsum[cur * 128 + c], sm);
      if (c == 0) atomicAdd(&gcnt[cur], (float)cnt);
      mx = 0.f; sm = 0.f; cnt = 0; cur = g;
    }
    float v = h[(size_t)i * 128 + c];
    mx = fmaxf(mx, v);
    sm += v;
    ++cnt;
  }
  atomicMax((int*)&gmax[cur * 128 + c], __float_as_int(mx));
  atomicAdd(&gsum[cur * 128 + c], sm);
  if (c == 0) atomicAdd(&gcnt[cur], (float)cnt);
}

// ---------------- MLP: one block per graph row ----------------

__global__ __launch_bounds__(128) void mlp_kernel(const float* __restrict__ gmax,
    const float* __restrict__ gsum, const float* __restrict__ gcnt,
    const float* __restrict__ rho,
    const float* __restrict__ w1, const float* __restrict__ b1,
    const float* __restrict__ w2, const float* __restrict__ b2,
    const float* __restrict__ w3, const float* __restrict__ b3,
    float* __restrict__ out) {
  __shared__ float s_in[257];
  __shared__ float s_z1[128];
  __shared__ float s_z2[128];
  int g = blockIdx.x, t = threadIdx.x;
  float inv_cnt = 1.f / fmaxf(gcnt[g], 1.f);
  s_in[t] = gmax[g * 128 + t];
  s_in[128 + t] = gsum[g * 128 + t] * inv_cnt;
  if (t == 0) s_in[256] = rho[g];
  __syncthreads();
  float s = b1[t];
  for (int k = 0; k < 257; ++k) s += s_in[k] * w1[k * 128 + t];
  s_z1[t] = relu_f(s);
  __syncthreads();
  s = b2[t];
  for (int k = 0; k < 128; ++k) s += s_z1[k] * w2[k * 128 + t];
  s_z2[t] = relu_f(s);
  __syncthreads();
  if (t < 36) {
    s = b3[t];
    for (int k = 0; k < 128; ++k) s += s_z2[k] * w3[k * 36 + t];
    out[g * 36 + t] = s;
  }
}

// ---------------- launch ----------------

extern "C" void kernel_launch(void* const* d_in, const int* in_sizes, int n_in,
                              void* d_out, int out_size, void* d_ws, size_t ws_size,
                              hipStream_t stream) {
  const float* x      = (const float*)d_in[0];
  const float* ew     = (const float*)d_in[1];
  const float* rho    = (const float*)d_in[2];
  const float* conv_w = (const float*)d_in[3];
  const float* conv_b = (const float*)d_in[4];
  const float* w1 = (const float*)d_in[5];
  const float* b1 = (const float*)d_in[6];
  const float* w2 = (const float*)d_in[7];
  const float* b2 = (const float*)d_in[8];
  const float* w3 = (const float*)d_in[9];
  const float* b3 = (const float*)d_in[10];
  const int* eidx  = (const int*)d_in[11];
  const int* batch = (const int*)d_in[12];

  const int N = in_sizes[0] / 128;
  const int E = in_sizes[1];
  const int G = in_sizes[2];
  const int* srcp = eidx;
  const int* dstp = eidx + E;

  const int NB = (N + 1023) / 1024;  // scan blocks (40 for N=40000)

  char* p = (char*)d_ws;
  auto carve = [&](size_t bytes) { char* r = p; p += (bytes + 255) & ~(size_t)255; return (void*)r; };
  float* deg    = (float*)carve((size_t)N * 4);
  float* dinv   = (float*)carve((size_t)N * 4);
  int*   indeg  = (int*)  carve((size_t)N * 4);
  int*   rowptr = (int*)  carve((size_t)(N + 1) * 4);
  int*   cursor = (int*)  carve((size_t)(N + 1) * 4);
  int*   bsum   = (int*)  carve((size_t)NB * 4);
  int2*  epack  = (int2*) carve((size_t)E * 8);
  float* agg    = (float*)carve((size_t)N * 128 * 4);  // reused in-place as h
  float* gmax   = (float*)carve((size_t)G * 128 * 4);
  float* gsum   = (float*)carve((size_t)G * 128 * 4);
  float* gcnt   = (float*)carve((size_t)G * 4);

  init_kernel<<<(N + 255) / 256, 256, 0, stream>>>(deg, indeg, gmax, gsum, gcnt, N, G * 128);
  edge_count_kernel<<<(E + 255) / 256, 256, 0, stream>>>(dstp, ew, deg, indeg, E);
  dinv_kernel<<<(N + 255) / 256, 256, 0, stream>>>(deg, dinv, N);
  scan_reduce_kernel<<<NB, 1024, 0, stream>>>(indeg, bsum, N);
  scan_bsum_kernel<<<1, 1024, 0, stream>>>(bsum, NB);
  scan_write_kernel<<<NB, 1024, 0, stream>>>(indeg, bsum, rowptr, cursor, N);
  edge_fill_kernel<<<(E + 255) / 256, 256, 0, stream>>>(srcp, dstp, ew, dinv, cursor, epack, E);
  aggregate_kernel<<<(N + 3) / 4, 256, 0, stream>>>((const float2*)x, dinv, rowptr, epack,
                                                    (float2*)agg, N);
  gemm_relu_kernel<<<(N + 31) / 32, 256, 0, stream>>>((const float4*)agg, conv_w, conv_b,
                                                      (float4*)agg, N);
  pool_kernel<<<(N + POOL_CHUNK - 1) / POOL_CHUNK, 128, 0, stream>>>(agg, batch, gmax, gsum,
                                                                     gcnt, N);
  mlp_kernel<<<G, 128, 0, stream>>>(gmax, gsum, gcnt, rho, w1, b1, w2, b2, w3, b3,
                                    (float*)d_out);
}

// Round 4
// 301.638 us; speedup vs baseline: 1.8411x; 1.0721x over previous
//
#include <hip/hip_runtime.h>
#include <hip/hip_bf16.h>

static __device__ __forceinline__ float relu_f(float v) { return v > 0.f ? v : 0.f; }

// ---------------- CSR build ----------------

__global__ void init_kernel(float* __restrict__ deg, int* __restrict__ indeg,
                            float* __restrict__ gmax, float* __restrict__ gsum,
                            float* __restrict__ gcnt, int n, int gch) {
  int i = blockIdx.x * blockDim.x + threadIdx.x;
  if (i < n) { deg[i] = 1.0f; indeg[i] = 0; }  // 1.0 = self-loop weight
  if (i < gch) { gmax[i] = 0.f; gsum[i] = 0.f; }
  if (i < (gch >> 7)) gcnt[i] = 0.f;
}

__global__ void edge_count_kernel(const int* __restrict__ dst, const float* __restrict__ ew,
                                  float* __restrict__ deg, int* __restrict__ indeg, int E) {
  int e = blockIdx.x * blockDim.x + threadIdx.x;
  if (e >= E) return;
  int d = dst[e];
  atomicAdd(&deg[d], ew[e]);
  atomicAdd(&indeg[d], 1);
}

__global__ void dinv_kernel(const float* __restrict__ deg, float* __restrict__ dinv, int n) {
  int i = blockIdx.x * blockDim.x + threadIdx.x;
  if (i < n) { float d = deg[i]; dinv[i] = (d > 0.f) ? rsqrtf(d) : 0.f; }
}

// ---------------- device-wide exclusive scan of indeg (3 kernels) ----------------

__global__ __launch_bounds__(1024) void scan_reduce_kernel(const int* __restrict__ indeg,
                                                           int* __restrict__ bsum, int n) {
  int i = blockIdx.x * 1024 + threadIdx.x;
  int v = (i < n) ? indeg[i] : 0;
  #pragma unroll
  for (int off = 32; off; off >>= 1) v += __shfl_down(v, off, 64);
  __shared__ int ws[16];
  int lane = threadIdx.x & 63, wid = threadIdx.x >> 6;
  if (lane == 0) ws[wid] = v;
  __syncthreads();
  if (threadIdx.x == 0) {
    int s = 0;
    #pragma unroll
    for (int j = 0; j < 16; ++j) s += ws[j];
    bsum[blockIdx.x] = s;
  }
}

__global__ __launch_bounds__(1024) void scan_bsum_kernel(int* __restrict__ bsum, int nb) {
  int t = threadIdx.x;
  int v = (t < nb) ? bsum[t] : 0;
  int lane = t & 63, wid = t >> 6;
  int inc = v;
  #pragma unroll
  for (int off = 1; off < 64; off <<= 1) {
    int u = __shfl_up(inc, off, 64);
    if (lane >= off) inc += u;
  }
  __shared__ int wtot[16];
  if (lane == 63) wtot[wid] = inc;
  __syncthreads();
  int woff = 0;
  for (int j = 0; j < wid; ++j) woff += wtot[j];
  if (t < nb) bsum[t] = woff + inc - v;  // exclusive
}

__global__ __launch_bounds__(1024) void scan_write_kernel(const int* __restrict__ indeg,
    const int* __restrict__ bsum, int* __restrict__ rowptr, int* __restrict__ cursor, int n) {
  int i = blockIdx.x * 1024 + threadIdx.x;
  int v = (i < n) ? indeg[i] : 0;
  int lane = threadIdx.x & 63, wid = threadIdx.x >> 6;
  int inc = v;
  #pragma unroll
  for (int off = 1; off < 64; off <<= 1) {
    int u = __shfl_up(inc, off, 64);
    if (lane >= off) inc += u;
  }
  __shared__ int wtot[16];
  if (lane == 63) wtot[wid] = inc;
  __syncthreads();
  int woff = 0;
  for (int j = 0; j < wid; ++j) woff += wtot[j];
  int excl = bsum[blockIdx.x] + woff + inc - v;
  if (i < n) {
    cursor[i] = excl;
    rowptr[i + 1] = excl + v;
    if (i == 0) rowptr[0] = 0;
  }
}

__global__ void edge_fill_kernel(const int* __restrict__ src, const int* __restrict__ dst,
                                 const float* __restrict__ ew, const float* __restrict__ dinv,
                                 int* __restrict__ cursor, int2* __restrict__ epack, int E) {
  int e = blockIdx.x * blockDim.x + threadIdx.x;
  if (e >= E) return;
  int sN = src[e], d = dst[e];
  int p = atomicAdd(&cursor[d], 1);
  float w = dinv[sN] * ew[e] * dinv[d];
  epack[p] = make_int2(sN, __float_as_int(w));
}

// ---------------- aggregation: one wave per node, 4 gathers in flight ----------------

__global__ __launch_bounds__(256) void aggregate_kernel(const float2* __restrict__ x2,
    const float* __restrict__ dinv, const int* __restrict__ rowptr,
    const int2* __restrict__ epack, float2* __restrict__ agg2, int n) {
  int gid = blockIdx.x * blockDim.x + threadIdx.x;
  int node = gid >> 6;
  int lane = gid & 63;
  if (node >= n) return;
  float di = dinv[node];
  float2 xv = x2[node * 64 + lane];
  float sw = di * di;  // self-loop norm: dinv*1*dinv
  float2 acc = make_float2(sw * xv.x, sw * xv.y);
  int s = rowptr[node], e = rowptr[node + 1];
  int j = s;
  // 4-way unroll: 4 epack loads then 4 independent row gathers in flight
  for (; j + 4 <= e; j += 4) {
    int2 p0 = epack[j + 0];
    int2 p1 = epack[j + 1];
    int2 p2 = epack[j + 2];
    int2 p3 = epack[j + 3];
    float2 a0 = x2[(size_t)p0.x * 64 + lane];
    float2 a1 = x2[(size_t)p1.x * 64 + lane];
    float2 a2 = x2[(size_t)p2.x * 64 + lane];
    float2 a3 = x2[(size_t)p3.x * 64 + lane];
    float w0 = __int_as_float(p0.y), w1 = __int_as_float(p1.y);
    float w2 = __int_as_float(p2.y), w3 = __int_as_float(p3.y);
    acc.x += w0 * a0.x; acc.y += w0 * a0.y;
    acc.x += w1 * a1.x; acc.y += w1 * a1.y;
    acc.x += w2 * a2.x; acc.y += w2 * a2.y;
    acc.x += w3 * a3.x; acc.y += w3 * a3.y;
  }
  for (; j < e; ++j) {
    int2 pk = epack[j];
    float w = __int_as_float(pk.y);
    float2 xc = x2[(size_t)pk.x * 64 + lane];
    acc.x += w * xc.x;
    acc.y += w * xc.y;
  }
  agg2[node * 64 + lane] = acc;
}

// ---------------- GEMM (agg @ W + b, ReLU), f32, 32 rows/block ----------------

__global__ __launch_bounds__(256) void gemm_relu_kernel(const float4* __restrict__ agg4,
    const float* __restrict__ W, const float* __restrict__ bias,
    float4* __restrict__ h4, int n) {
  __shared__ float sA[32 * 128];   // 16 KB
  __shared__ float sW[64 * 128];   // 32 KB (two K-chunks)
  int tid = threadIdx.x;
  int row0 = blockIdx.x * 32;
  int nb = n - row0; if (nb > 32) nb = 32;
  float4* sA4 = (float4*)sA;
  for (int idx = tid; idx < 32 * 32; idx += 256) {
    int r = idx >> 5;
    sA4[idx] = (r < nb) ? agg4[(size_t)row0 * 32 + idx] : make_float4(0.f, 0.f, 0.f, 0.f);
  }
  int tx = tid & 31, ty = tid >> 5;   // cols 4*tx..+3, rows 4*ty..+3
  float acc[4][4] = {};
  const float4* W4 = (const float4*)W;
  float4* sW4 = (float4*)sW;
  for (int kk = 0; kk < 128; kk += 64) {
    __syncthreads();
    for (int idx = tid; idx < 64 * 32; idx += 256)
      sW4[idx] = W4[kk * 32 + idx];
    __syncthreads();
    #pragma unroll 8
    for (int k = 0; k < 64; ++k) {
      float a0 = sA[(4 * ty + 0) * 128 + kk + k];
      float a1 = sA[(4 * ty + 1) * 128 + kk + k];
      float a2 = sA[(4 * ty + 2) * 128 + kk + k];
      float a3 = sA[(4 * ty + 3) * 128 + kk + k];
      float4 wv = *(const float4*)&sW[k * 128 + 4 * tx];
      acc[0][0] += a0 * wv.x; acc[0][1] += a0 * wv.y; acc[0][2] += a0 * wv.z; acc[0][3] += a0 * wv.w;
      acc[1][0] += a1 * wv.x; acc[1][1] += a1 * wv.y; acc[1][2] += a1 * wv.z; acc[1][3] += a1 * wv.w;
      acc[2][0] += a2 * wv.x; acc[2][1] += a2 * wv.y; acc[2][2] += a2 * wv.z; acc[2][3] += a2 * wv.w;
      acc[3][0] += a3 * wv.x; acc[3][1] += a3 * wv.y; acc[3][2] += a3 * wv.z; acc[3][3] += a3 * wv.w;
    }
  }
  float4 bb = ((const float4*)bias)[tx];
  #pragma unroll
  for (int i = 0; i < 4; ++i) {
    int r = 4 * ty + i;
    if (r < nb) {
      float4 o;
      o.x = relu_f(acc[i][0] + bb.x);
      o.y = relu_f(acc[i][1] + bb.y);
      o.z = relu_f(acc[i][2] + bb.z);
      o.w = relu_f(acc[i][3] + bb.w);
      h4[(size_t)(row0 + r) * 32 + tx] = o;
    }
  }
}

// ---------------- pooling: node-parallel partial reduce + atomic flush ----------------

#define POOL_CHUNK 64

__global__ __launch_bounds__(128) void pool_kernel(const float* __restrict__ h,
    const int* __restrict__ batch, float* __restrict__ gmax, float* __restrict__ gsum,
    float* __restrict__ gcnt, int n) {
  int c = threadIdx.x;
  int n0 = blockIdx.x * POOL_CHUNK;
  if (n0 >= n) return;
  int n1 = n0 + POOL_CHUNK; if (n1 > n) n1 = n;
  float mx = 0.f, sm = 0.f;
  int cnt = 0;
  int cur = batch[n0];
  for (int i = n0; i < n1; ++i) {
    int g = batch[i];
    if (g != cur) {
      atomicMax((int*)&gmax[cur * 128 + c], __float_as_int(mx));
      atomicAdd(&gsum[cur * 128 + c], sm);
      if (c == 0) atomicAdd(&gcnt[cur], (float)cnt);
      mx = 0.f; sm = 0.f; cnt = 0; cur = g;
    }
    float v = h[(size_t)i * 128 + c];
    mx = fmaxf(mx, v);
    sm += v;
    ++cnt;
  }
  atomicMax((int*)&gmax[cur * 128 + c], __float_as_int(mx));
  atomicAdd(&gsum[cur * 128 + c], sm);
  if (c == 0) atomicAdd(&gcnt[cur], (float)cnt);
}

// ---------------- MLP: one block per graph row ----------------

__global__ __launch_bounds__(128) void mlp_kernel(const float* __restrict__ gmax,
    const float* __restrict__ gsum, const float* __restrict__ gcnt,
    const float* __restrict__ rho,
    const float* __restrict__ w1, const float* __restrict__ b1,
    const float* __restrict__ w2, const float* __restrict__ b2,
    const float* __restrict__ w3, const float* __restrict__ b3,
    float* __restrict__ out) {
  __shared__ float s_in[257];
  __shared__ float s_z1[128];
  __shared__ float s_z2[128];
  int g = blockIdx.x, t = threadIdx.x;
  float inv_cnt = 1.f / fmaxf(gcnt[g], 1.f);
  s_in[t] = gmax[g * 128 + t];
  s_in[128 + t] = gsum[g * 128 + t] * inv_cnt;
  if (t == 0) s_in[256] = rho[g];
  __syncthreads();
  float s = b1[t];
  for (int k = 0; k < 257; ++k) s += s_in[k] * w1[k * 128 + t];
  s_z1[t] = relu_f(s);
  __syncthreads();
  s = b2[t];
  for (int k = 0; k < 128; ++k) s += s_z1[k] * w2[k * 128 + t];
  s_z2[t] = relu_f(s);
  __syncthreads();
  if (t < 36) {
    s = b3[t];
    for (int k = 0; k < 128; ++k) s += s_z2[k] * w3[k * 36 + t];
    out[g * 36 + t] = s;
  }
}

// ---------------- launch ----------------

extern "C" void kernel_launch(void* const* d_in, const int* in_sizes, int n_in,
                              void* d_out, int out_size, void* d_ws, size_t ws_size,
                              hipStream_t stream) {
  const float* x      = (const float*)d_in[0];
  const float* ew     = (const float*)d_in[1];
  const float* rho    = (const float*)d_in[2];
  const float* conv_w = (const float*)d_in[3];
  const float* conv_b = (const float*)d_in[4];
  const float* w1 = (const float*)d_in[5];
  const float* b1 = (const float*)d_in[6];
  const float* w2 = (const float*)d_in[7];
  const float* b2 = (const float*)d_in[8];
  const float* w3 = (const float*)d_in[9];
  const float* b3 = (const float*)d_in[10];
  const int* eidx  = (const int*)d_in[11];
  const int* batch = (const int*)d_in[12];

  const int N = in_sizes[0] / 128;
  const int E = in_sizes[1];
  const int G = in_sizes[2];
  const int* srcp = eidx;
  const int* dstp = eidx + E;

  const int NB = (N + 1023) / 1024;  // scan blocks (40 for N=40000)

  char* p = (char*)d_ws;
  auto carve = [&](size_t bytes) { char* r = p; p += (bytes + 255) & ~(size_t)255; return (void*)r; };
  float* deg    = (float*)carve((size_t)N * 4);
  float* dinv   = (float*)carve((size_t)N * 4);
  int*   indeg  = (int*)  carve((size_t)N * 4);
  int*   rowptr = (int*)  carve((size_t)(N + 1) * 4);
  int*   cursor = (int*)  carve((size_t)(N + 1) * 4);
  int*   bsum   = (int*)  carve((size_t)NB * 4);
  int2*  epack  = (int2*) carve((size_t)E * 8);
  float* agg    = (float*)carve((size_t)N * 128 * 4);  // reused in-place as h
  float* gmax   = (float*)carve((size_t)G * 128 * 4);
  float* gsum   = (float*)carve((size_t)G * 128 * 4);
  float* gcnt   = (float*)carve((size_t)G * 4);

  init_kernel<<<(N + 255) / 256, 256, 0, stream>>>(deg, indeg, gmax, gsum, gcnt, N, G * 128);
  edge_count_kernel<<<(E + 255) / 256, 256, 0, stream>>>(dstp, ew, deg, indeg, E);
  dinv_kernel<<<(N + 255) / 256, 256, 0, stream>>>(deg, dinv, N);
  scan_reduce_kernel<<<NB, 1024, 0, stream>>>(indeg, bsum, N);
  scan_bsum_kernel<<<1, 1024, 0, stream>>>(bsum, NB);
  scan_write_kernel<<<NB, 1024, 0, stream>>>(indeg, bsum, rowptr, cursor, N);
  edge_fill_kernel<<<(E + 255) / 256, 256, 0, stream>>>(srcp, dstp, ew, dinv, cursor, epack, E);
  aggregate_kernel<<<(N + 3) / 4, 256, 0, stream>>>((const float2*)x, dinv, rowptr, epack,
                                                    (float2*)agg, N);
  gemm_relu_kernel<<<(N + 31) / 32, 256, 0, stream>>>((const float4*)agg, conv_w, conv_b,
                                                      (float4*)agg, N);
  pool_kernel<<<(N + POOL_CHUNK - 1) / POOL_CHUNK, 128, 0, stream>>>(agg, batch, gmax, gsum,
                                                                     gcnt, N);
  mlp_kernel<<<G, 128, 0, stream>>>(gmax, gsum, gcnt, rho, w1, b1, w2, b2, w3, b3,
                                    (float*)d_out);
}

// Round 5
// 256.360 us; speedup vs baseline: 2.1663x; 1.1766x over previous
//
#include <hip/hip_runtime.h>
#include <hip/hip_bf16.h>

static __device__ __forceinline__ float relu_f(float v) { return v > 0.f ? v : 0.f; }

// ---------------- CSR build ----------------

__global__ void init_kernel(int* __restrict__ indeg,
                            float* __restrict__ gmax, float* __restrict__ gsum,
                            float* __restrict__ gcnt, int n, int gch) {
  int i = blockIdx.x * blockDim.x + threadIdx.x;
  if (i < n) indeg[i] = 0;
  if (i < gch) { gmax[i] = 0.f; gsum[i] = 0.f; }
  if (i < (gch >> 7)) gcnt[i] = 0.f;
}

// one atomic per edge; rank = within-bucket arrival order
__global__ void count_rank_kernel(const int* __restrict__ dst, int* __restrict__ indeg,
                                  int* __restrict__ rank, int E) {
  int e = blockIdx.x * blockDim.x + threadIdx.x;
  if (e >= E) return;
  rank[e] = atomicAdd(&indeg[dst[e]], 1);
}

// ---------------- device-wide exclusive scan of indeg (3 kernels) ----------------

__global__ __launch_bounds__(1024) void scan_reduce_kernel(const int* __restrict__ indeg,
                                                           int* __restrict__ bsum, int n) {
  int i = blockIdx.x * 1024 + threadIdx.x;
  int v = (i < n) ? indeg[i] : 0;
  #pragma unroll
  for (int off = 32; off; off >>= 1) v += __shfl_down(v, off, 64);
  __shared__ int ws[16];
  int lane = threadIdx.x & 63, wid = threadIdx.x >> 6;
  if (lane == 0) ws[wid] = v;
  __syncthreads();
  if (threadIdx.x == 0) {
    int s = 0;
    #pragma unroll
    for (int j = 0; j < 16; ++j) s += ws[j];
    bsum[blockIdx.x] = s;
  }
}

__global__ __launch_bounds__(1024) void scan_bsum_kernel(int* __restrict__ bsum, int nb) {
  int t = threadIdx.x;
  int v = (t < nb) ? bsum[t] : 0;
  int lane = t & 63, wid = t >> 6;
  int inc = v;
  #pragma unroll
  for (int off = 1; off < 64; off <<= 1) {
    int u = __shfl_up(inc, off, 64);
    if (lane >= off) inc += u;
  }
  __shared__ int wtot[16];
  if (lane == 63) wtot[wid] = inc;
  __syncthreads();
  int woff = 0;
  for (int j = 0; j < wid; ++j) woff += wtot[j];
  if (t < nb) bsum[t] = woff + inc - v;  // exclusive
}

__global__ __launch_bounds__(1024) void scan_write_kernel(const int* __restrict__ indeg,
    const int* __restrict__ bsum, int* __restrict__ rowptr, int n) {
  int i = blockIdx.x * 1024 + threadIdx.x;
  int v = (i < n) ? indeg[i] : 0;
  int lane = threadIdx.x & 63, wid = threadIdx.x >> 6;
  int inc = v;
  #pragma unroll
  for (int off = 1; off < 64; off <<= 1) {
    int u = __shfl_up(inc, off, 64);
    if (lane >= off) inc += u;
  }
  __shared__ int wtot[16];
  if (lane == 63) wtot[wid] = inc;
  __syncthreads();
  int woff = 0;
  for (int j = 0; j < wid; ++j) woff += wtot[j];
  int excl = bsum[blockIdx.x] + woff + inc - v;
  if (i < n) {
    rowptr[i + 1] = excl + v;
    if (i == 0) rowptr[0] = 0;
  }
}

// no atomics: slot = rowptr[dst] + rank
__global__ void edge_fill_kernel(const int* __restrict__ src, const int* __restrict__ dst,
                                 const float* __restrict__ ew, const int* __restrict__ rank,
                                 const int* __restrict__ rowptr, int2* __restrict__ epack,
                                 int E) {
  int e = blockIdx.x * blockDim.x + threadIdx.x;
  if (e >= E) return;
  int d = dst[e];
  int slot = rowptr[d] + rank[e];
  epack[slot] = make_int2(src[e], __float_as_int(ew[e]));
}

// deg[i] = 1 + sum of ew over row i (contiguous read); dinv = rsqrt
__global__ void row_dinv_kernel(const int* __restrict__ rowptr, const int2* __restrict__ epack,
                                float* __restrict__ dinv, int n) {
  int i = blockIdx.x * blockDim.x + threadIdx.x;
  if (i >= n) return;
  int s = rowptr[i], e = rowptr[i + 1];
  float d = 1.0f;  // self-loop weight
  for (int j = s; j < e; ++j) d += __int_as_float(epack[j].y);
  dinv[i] = (d > 0.f) ? rsqrtf(d) : 0.f;
}

// ---------------- aggregation: one wave per node, 4 gathers in flight ----------------
// epack holds (src, raw ew); norm = dinv[src]*ew*dinv[node] computed in-loop
// (dinv[src] is a wave-uniform broadcast load from a 160 KB L2-resident table).

__global__ __launch_bounds__(256) void aggregate_kernel(const float2* __restrict__ x2,
    const float* __restrict__ dinv, const int* __restrict__ rowptr,
    const int2* __restrict__ epack, float2* __restrict__ agg2, int n) {
  int gid = blockIdx.x * blockDim.x + threadIdx.x;
  int node = gid >> 6;
  int lane = gid & 63;
  if (node >= n) return;
  float dn = dinv[node];
  float2 xv = x2[node * 64 + lane];
  float sw = dn * dn;  // self-loop norm
  float2 acc = make_float2(sw * xv.x, sw * xv.y);
  int s = rowptr[node], e = rowptr[node + 1];
  int j = s;
  for (; j + 4 <= e; j += 4) {
    int2 p0 = epack[j + 0];
    int2 p1 = epack[j + 1];
    int2 p2 = epack[j + 2];
    int2 p3 = epack[j + 3];
    float d0 = dinv[p0.x], d1 = dinv[p1.x], d2 = dinv[p2.x], d3 = dinv[p3.x];
    float2 a0 = x2[(size_t)p0.x * 64 + lane];
    float2 a1 = x2[(size_t)p1.x * 64 + lane];
    float2 a2 = x2[(size_t)p2.x * 64 + lane];
    float2 a3 = x2[(size_t)p3.x * 64 + lane];
    float w0 = d0 * __int_as_float(p0.y) * dn;
    float w1 = d1 * __int_as_float(p1.y) * dn;
    float w2 = d2 * __int_as_float(p2.y) * dn;
    float w3 = d3 * __int_as_float(p3.y) * dn;
    acc.x += w0 * a0.x; acc.y += w0 * a0.y;
    acc.x += w1 * a1.x; acc.y += w1 * a1.y;
    acc.x += w2 * a2.x; acc.y += w2 * a2.y;
    acc.x += w3 * a3.x; acc.y += w3 * a3.y;
  }
  for (; j < e; ++j) {
    int2 pk = epack[j];
    float w = dinv[pk.x] * __int_as_float(pk.y) * dn;
    float2 xc = x2[(size_t)pk.x * 64 + lane];
    acc.x += w * xc.x;
    acc.y += w * xc.y;
  }
  agg2[node * 64 + lane] = acc;
}

// ---------------- GEMM (agg @ W + b, ReLU), f32, 32 rows/block ----------------

__global__ __launch_bounds__(256) void gemm_relu_kernel(const float4* __restrict__ agg4,
    const float* __restrict__ W, const float* __restrict__ bias,
    float4* __restrict__ h4, int n) {
  __shared__ float sA[32 * 128];   // 16 KB
  __shared__ float sW[64 * 128];   // 32 KB (two K-chunks)
  int tid = threadIdx.x;
  int row0 = blockIdx.x * 32;
  int nb = n - row0; if (nb > 32) nb = 32;
  float4* sA4 = (float4*)sA;
  for (int idx = tid; idx < 32 * 32; idx += 256) {
    int r = idx >> 5;
    sA4[idx] = (r < nb) ? agg4[(size_t)row0 * 32 + idx] : make_float4(0.f, 0.f, 0.f, 0.f);
  }
  int tx = tid & 31, ty = tid >> 5;   // cols 4*tx..+3, rows 4*ty..+3
  float acc[4][4] = {};
  const float4* W4 = (const float4*)W;
  float4* sW4 = (float4*)sW;
  for (int kk = 0; kk < 128; kk += 64) {
    __syncthreads();
    for (int idx = tid; idx < 64 * 32; idx += 256)
      sW4[idx] = W4[kk * 32 + idx];
    __syncthreads();
    #pragma unroll 8
    for (int k = 0; k < 64; ++k) {
      float a0 = sA[(4 * ty + 0) * 128 + kk + k];
      float a1 = sA[(4 * ty + 1) * 128 + kk + k];
      float a2 = sA[(4 * ty + 2) * 128 + kk + k];
      float a3 = sA[(4 * ty + 3) * 128 + kk + k];
      float4 wv = *(const float4*)&sW[k * 128 + 4 * tx];
      acc[0][0] += a0 * wv.x; acc[0][1] += a0 * wv.y; acc[0][2] += a0 * wv.z; acc[0][3] += a0 * wv.w;
      acc[1][0] += a1 * wv.x; acc[1][1] += a1 * wv.y; acc[1][2] += a1 * wv.z; acc[1][3] += a1 * wv.w;
      acc[2][0] += a2 * wv.x; acc[2][1] += a2 * wv.y; acc[2][2] += a2 * wv.z; acc[2][3] += a2 * wv.w;
      acc[3][0] += a3 * wv.x; acc[3][1] += a3 * wv.y; acc[3][2] += a3 * wv.z; acc[3][3] += a3 * wv.w;
    }
  }
  float4 bb = ((const float4*)bias)[tx];
  #pragma unroll
  for (int i = 0; i < 4; ++i) {
    int r = 4 * ty + i;
    if (r < nb) {
      float4 o;
      o.x = relu_f(acc[i][0] + bb.x);
      o.y = relu_f(acc[i][1] + bb.y);
      o.z = relu_f(acc[i][2] + bb.z);
      o.w = relu_f(acc[i][3] + bb.w);
      h4[(size_t)(row0 + r) * 32 + tx] = o;
    }
  }
}

// ---------------- pooling: node-parallel partial reduce + atomic flush ----------------

#define POOL_CHUNK 64

__global__ __launch_bounds__(128) void pool_kernel(const float* __restrict__ h,
    const int* __restrict__ batch, float* __restrict__ gmax, float* __restrict__ gsum,
    float* __restrict__ gcnt, int n) {
  int c = threadIdx.x;
  int n0 = blockIdx.x * POOL_CHUNK;
  if (n0 >= n) return;
  int n1 = n0 + POOL_CHUNK; if (n1 > n) n1 = n;
  float mx = 0.f, sm = 0.f;
  int cnt = 0;
  int cur = batch[n0];
  for (int i = n0; i < n1; ++i) {
    int g = batch[i];
    if (g != cur) {
      atomicMax((int*)&gmax[cur * 128 + c], __float_as_int(mx));
      atomicAdd(&gsum[cur * 128 + c], sm);
      if (c == 0) atomicAdd(&gcnt[cur], (float)cnt);
      mx = 0.f; sm = 0.f; cnt = 0; cur = g;
    }
    float v = h[(size_t)i * 128 + c];
    mx = fmaxf(mx, v);
    sm += v;
    ++cnt;
  }
  atomicMax((int*)&gmax[cur * 128 + c], __float_as_int(mx));
  atomicAdd(&gsum[cur * 128 + c], sm);
  if (c == 0) atomicAdd(&gcnt[cur], (float)cnt);
}

// ---------------- MLP: one block per graph row ----------------

__global__ __launch_bounds__(128) void mlp_kernel(const float* __restrict__ gmax,
    const float* __restrict__ gsum, const float* __restrict__ gcnt,
    const float* __restrict__ rho,
    const float* __restrict__ w1, const float* __restrict__ b1,
    const float* __restrict__ w2, const float* __restrict__ b2,
    const float* __restrict__ w3, const float* __restrict__ b3,
    float* __restrict__ out) {
  __shared__ float s_in[257];
  __shared__ float s_z1[128];
  __shared__ float s_z2[128];
  int g = blockIdx.x, t = threadIdx.x;
  float inv_cnt = 1.f / fmaxf(gcnt[g], 1.f);
  s_in[t] = gmax[g * 128 + t];
  s_in[128 + t] = gsum[g * 128 + t] * inv_cnt;
  if (t == 0) s_in[256] = rho[g];
  __syncthreads();
  float s = b1[t];
  for (int k = 0; k < 257; ++k) s += s_in[k] * w1[k * 128 + t];
  s_z1[t] = relu_f(s);
  __syncthreads();
  s = b2[t];
  for (int k = 0; k < 128; ++k) s += s_z1[k] * w2[k * 128 + t];
  s_z2[t] = relu_f(s);
  __syncthreads();
  if (t < 36) {
    s = b3[t];
    for (int k = 0; k < 128; ++k) s += s_z2[k] * w3[k * 36 + t];
    out[g * 36 + t] = s;
  }
}

// ---------------- launch ----------------

extern "C" void kernel_launch(void* const* d_in, const int* in_sizes, int n_in,
                              void* d_out, int out_size, void* d_ws, size_t ws_size,
                              hipStream_t stream) {
  const float* x      = (const float*)d_in[0];
  const float* ew     = (const float*)d_in[1];
  const float* rho    = (const float*)d_in[2];
  const float* conv_w = (const float*)d_in[3];
  const float* conv_b = (const float*)d_in[4];
  const float* w1 = (const float*)d_in[5];
  const float* b1 = (const float*)d_in[6];
  const float* w2 = (const float*)d_in[7];
  const float* b2 = (const float*)d_in[8];
  const float* w3 = (const float*)d_in[9];
  const float* b3 = (const float*)d_in[10];
  const int* eidx  = (const int*)d_in[11];
  const int* batch = (const int*)d_in[12];

  const int N = in_sizes[0] / 128;
  const int E = in_sizes[1];
  const int G = in_sizes[2];
  const int* srcp = eidx;
  const int* dstp = eidx + E;

  const int NB = (N + 1023) / 1024;  // scan blocks (40 for N=40000)

  char* p = (char*)d_ws;
  auto carve = [&](size_t bytes) { char* r = p; p += (bytes + 255) & ~(size_t)255; return (void*)r; };
  float* dinv   = (float*)carve((size_t)N * 4);
  int*   indeg  = (int*)  carve((size_t)N * 4);
  int*   rowptr = (int*)  carve((size_t)(N + 1) * 4);
  int*   rank   = (int*)  carve((size_t)E * 4);
  int*   bsum   = (int*)  carve((size_t)NB * 4);
  int2*  epack  = (int2*) carve((size_t)E * 8);
  float* agg    = (float*)carve((size_t)N * 128 * 4);  // reused in-place as h
  float* gmax   = (float*)carve((size_t)G * 128 * 4);
  float* gsum   = (float*)carve((size_t)G * 128 * 4);
  float* gcnt   = (float*)carve((size_t)G * 4);

  init_kernel<<<(N + 255) / 256, 256, 0, stream>>>(indeg, gmax, gsum, gcnt, N, G * 128);
  count_rank_kernel<<<(E + 255) / 256, 256, 0, stream>>>(dstp, indeg, rank, E);
  scan_reduce_kernel<<<NB, 1024, 0, stream>>>(indeg, bsum, N);
  scan_bsum_kernel<<<1, 1024, 0, stream>>>(bsum, NB);
  scan_write_kernel<<<NB, 1024, 0, stream>>>(indeg, bsum, rowptr, N);
  edge_fill_kernel<<<(E + 255) / 256, 256, 0, stream>>>(srcp, dstp, ew, rank, rowptr, epack, E);
  row_dinv_kernel<<<(N + 255) / 256, 256, 0, stream>>>(rowptr, epack, dinv, N);
  aggregate_kernel<<<(N + 3) / 4, 256, 0, stream>>>((const float2*)x, dinv, rowptr, epack,
                                                    (float2*)agg, N);
  gemm_relu_kernel<<<(N + 31) / 32, 256, 0, stream>>>((const float4*)agg, conv_w, conv_b,
                                                      (float4*)agg, N);
  pool_kernel<<<(N + POOL_CHUNK - 1) / POOL_CHUNK, 128, 0, stream>>>(agg, batch, gmax, gsum,
                                                                     gcnt, N);
  mlp_kernel<<<G, 128, 0, stream>>>(gmax, gsum, gcnt, rho, w1, b1, w2, b2, w3, b3,
                                    (float*)d_out);
}

// Round 6
// 248.856 us; speedup vs baseline: 2.2316x; 1.0302x over previous
//
#include <hip/hip_runtime.h>
#include <hip/hip_bf16.h>
#include <hip/hip_fp16.h>

static __device__ __forceinline__ float relu_f(float v) { return v > 0.f ? v : 0.f; }

// ---------------- init + fp16 cast of x ----------------

__global__ void init_kernel(int* __restrict__ indeg,
                            float* __restrict__ gmax, float* __restrict__ gsum,
                            float* __restrict__ gcnt, int n, int gch) {
  int i = blockIdx.x * blockDim.x + threadIdx.x;
  if (i < n) indeg[i] = 0;
  if (i < gch) { gmax[i] = 0.f; gsum[i] = 0.f; }
  if (i < (gch >> 7)) gcnt[i] = 0.f;
}

// x (f32) -> xh (fp16), vectorized: 4 floats -> 4 halves per thread
__global__ void cast_kernel(const float4* __restrict__ x4, __half2* __restrict__ xh2, int n4) {
  int i = blockIdx.x * blockDim.x + threadIdx.x;
  if (i >= n4) return;
  float4 v = x4[i];
  xh2[2 * i + 0] = __floats2half2_rn(v.x, v.y);
  xh2[2 * i + 1] = __floats2half2_rn(v.z, v.w);
}

// one atomic per edge; rank = within-bucket arrival order
__global__ void count_rank_kernel(const int* __restrict__ dst, int* __restrict__ indeg,
                                  int* __restrict__ rank, int E) {
  int e = blockIdx.x * blockDim.x + threadIdx.x;
  if (e >= E) return;
  rank[e] = atomicAdd(&indeg[dst[e]], 1);
}

// ---------------- device-wide exclusive scan of indeg (3 kernels) ----------------

__global__ __launch_bounds__(1024) void scan_reduce_kernel(const int* __restrict__ indeg,
                                                           int* __restrict__ bsum, int n) {
  int i = blockIdx.x * 1024 + threadIdx.x;
  int v = (i < n) ? indeg[i] : 0;
  #pragma unroll
  for (int off = 32; off; off >>= 1) v += __shfl_down(v, off, 64);
  __shared__ int ws[16];
  int lane = threadIdx.x & 63, wid = threadIdx.x >> 6;
  if (lane == 0) ws[wid] = v;
  __syncthreads();
  if (threadIdx.x == 0) {
    int s = 0;
    #pragma unroll
    for (int j = 0; j < 16; ++j) s += ws[j];
    bsum[blockIdx.x] = s;
  }
}

__global__ __launch_bounds__(1024) void scan_bsum_kernel(int* __restrict__ bsum, int nb) {
  int t = threadIdx.x;
  int v = (t < nb) ? bsum[t] : 0;
  int lane = t & 63, wid = t >> 6;
  int inc = v;
  #pragma unroll
  for (int off = 1; off < 64; off <<= 1) {
    int u = __shfl_up(inc, off, 64);
    if (lane >= off) inc += u;
  }
  __shared__ int wtot[16];
  if (lane == 63) wtot[wid] = inc;
  __syncthreads();
  int woff = 0;
  for (int j = 0; j < wid; ++j) woff += wtot[j];
  if (t < nb) bsum[t] = woff + inc - v;  // exclusive
}

__global__ __launch_bounds__(1024) void scan_write_kernel(const int* __restrict__ indeg,
    const int* __restrict__ bsum, int* __restrict__ rowptr, int n) {
  int i = blockIdx.x * 1024 + threadIdx.x;
  int v = (i < n) ? indeg[i] : 0;
  int lane = threadIdx.x & 63, wid = threadIdx.x >> 6;
  int inc = v;
  #pragma unroll
  for (int off = 1; off < 64; off <<= 1) {
    int u = __shfl_up(inc, off, 64);
    if (lane >= off) inc += u;
  }
  __shared__ int wtot[16];
  if (lane == 63) wtot[wid] = inc;
  __syncthreads();
  int woff = 0;
  for (int j = 0; j < wid; ++j) woff += wtot[j];
  int excl = bsum[blockIdx.x] + woff + inc - v;
  if (i < n) {
    rowptr[i + 1] = excl + v;
    if (i == 0) rowptr[0] = 0;
  }
}

// no atomics: slot = rowptr[dst] + rank
__global__ void edge_fill_kernel(const int* __restrict__ src, const int* __restrict__ dst,
                                 const float* __restrict__ ew, const int* __restrict__ rank,
                                 const int* __restrict__ rowptr, int2* __restrict__ epack,
                                 int E) {
  int e = blockIdx.x * blockDim.x + threadIdx.x;
  if (e >= E) return;
  int d = dst[e];
  int slot = rowptr[d] + rank[e];
  epack[slot] = make_int2(src[e], __float_as_int(ew[e]));
}

// deg[i] = 1 + sum of ew over row i (contiguous read); dinv = rsqrt
__global__ void row_dinv_kernel(const int* __restrict__ rowptr, const int2* __restrict__ epack,
                                float* __restrict__ dinv, int n) {
  int i = blockIdx.x * blockDim.x + threadIdx.x;
  if (i >= n) return;
  int s = rowptr[i], e = rowptr[i + 1];
  float d = 1.0f;  // self-loop weight
  for (int j = s; j < e; ++j) d += __int_as_float(epack[j].y);
  dinv[i] = (d > 0.f) ? rsqrtf(d) : 0.f;
}

// ---------------- aggregation: one wave per node, fp16 gathers, 8 in flight ----------------
// epack holds (src, raw ew); norm = dinv[src]*ew*dinv[node] computed in-loop.
// Neighbor rows gathered from the fp16 copy (halves L2-miss traffic); self term f32.

__global__ __launch_bounds__(256) void aggregate_kernel(const float2* __restrict__ x2,
    const __half2* __restrict__ xh2,
    const float* __restrict__ dinv, const int* __restrict__ rowptr,
    const int2* __restrict__ epack, float2* __restrict__ agg2, int n) {
  int gid = blockIdx.x * blockDim.x + threadIdx.x;
  int node = gid >> 6;
  int lane = gid & 63;
  if (node >= n) return;
  float dn = dinv[node];
  float2 xv = x2[node * 64 + lane];
  float sw = dn * dn;  // self-loop norm
  float2 acc = make_float2(sw * xv.x, sw * xv.y);
  int s = rowptr[node], e = rowptr[node + 1];
  int j = s;
  for (; j + 8 <= e; j += 8) {
    int2 pk[8];
    #pragma unroll
    for (int u = 0; u < 8; ++u) pk[u] = epack[j + u];
    __half2 hx[8];
    float dw[8];
    #pragma unroll
    for (int u = 0; u < 8; ++u) {
      hx[u] = xh2[(size_t)pk[u].x * 64 + lane];
      dw[u] = dinv[pk[u].x];
    }
    #pragma unroll
    for (int u = 0; u < 8; ++u) {
      float w = dw[u] * __int_as_float(pk[u].y) * dn;
      float2 xc = __half22float2(hx[u]);
      acc.x += w * xc.x;
      acc.y += w * xc.y;
    }
  }
  for (; j < e; ++j) {
    int2 pk = epack[j];
    float w = dinv[pk.x] * __int_as_float(pk.y) * dn;
    float2 xc = __half22float2(xh2[(size_t)pk.x * 64 + lane]);
    acc.x += w * xc.x;
    acc.y += w * xc.y;
  }
  agg2[node * 64 + lane] = acc;
}

// ---------------- GEMM (agg @ W + b, ReLU), f32, 32 rows/block ----------------

__global__ __launch_bounds__(256) void gemm_relu_kernel(const float4* __restrict__ agg4,
    const float* __restrict__ W, const float* __restrict__ bias,
    float4* __restrict__ h4, int n) {
  __shared__ float sA[32 * 128];   // 16 KB
  __shared__ float sW[64 * 128];   // 32 KB (two K-chunks)
  int tid = threadIdx.x;
  int row0 = blockIdx.x * 32;
  int nb = n - row0; if (nb > 32) nb = 32;
  float4* sA4 = (float4*)sA;
  for (int idx = tid; idx < 32 * 32; idx += 256) {
    int r = idx >> 5;
    sA4[idx] = (r < nb) ? agg4[(size_t)row0 * 32 + idx] : make_float4(0.f, 0.f, 0.f, 0.f);
  }
  int tx = tid & 31, ty = tid >> 5;   // cols 4*tx..+3, rows 4*ty..+3
  float acc[4][4] = {};
  const float4* W4 = (const float4*)W;
  float4* sW4 = (float4*)sW;
  for (int kk = 0; kk < 128; kk += 64) {
    __syncthreads();
    for (int idx = tid; idx < 64 * 32; idx += 256)
      sW4[idx] = W4[kk * 32 + idx];
    __syncthreads();
    #pragma unroll 8
    for (int k = 0; k < 64; ++k) {
      float a0 = sA[(4 * ty + 0) * 128 + kk + k];
      float a1 = sA[(4 * ty + 1) * 128 + kk + k];
      float a2 = sA[(4 * ty + 2) * 128 + kk + k];
      float a3 = sA[(4 * ty + 3) * 128 + kk + k];
      float4 wv = *(const float4*)&sW[k * 128 + 4 * tx];
      acc[0][0] += a0 * wv.x; acc[0][1] += a0 * wv.y; acc[0][2] += a0 * wv.z; acc[0][3] += a0 * wv.w;
      acc[1][0] += a1 * wv.x; acc[1][1] += a1 * wv.y; acc[1][2] += a1 * wv.z; acc[1][3] += a1 * wv.w;
      acc[2][0] += a2 * wv.x; acc[2][1] += a2 * wv.y; acc[2][2] += a2 * wv.z; acc[2][3] += a2 * wv.w;
      acc[3][0] += a3 * wv.x; acc[3][1] += a3 * wv.y; acc[3][2] += a3 * wv.z; acc[3][3] += a3 * wv.w;
    }
  }
  float4 bb = ((const float4*)bias)[tx];
  #pragma unroll
  for (int i = 0; i < 4; ++i) {
    int r = 4 * ty + i;
    if (r < nb) {
      float4 o;
      o.x = relu_f(acc[i][0] + bb.x);
      o.y = relu_f(acc[i][1] + bb.y);
      o.z = relu_f(acc[i][2] + bb.z);
      o.w = relu_f(acc[i][3] + bb.w);
      h4[(size_t)(row0 + r) * 32 + tx] = o;
    }
  }
}

// ---------------- pooling: node-parallel partial reduce + atomic flush ----------------

#define POOL_CHUNK 64

__global__ __launch_bounds__(128) void pool_kernel(const float* __restrict__ h,
    const int* __restrict__ batch, float* __restrict__ gmax, float* __restrict__ gsum,
    float* __restrict__ gcnt, int n) {
  int c = threadIdx.x;
  int n0 = blockIdx.x * POOL_CHUNK;
  if (n0 >= n) return;
  int n1 = n0 + POOL_CHUNK; if (n1 > n) n1 = n;
  float mx = 0.f, sm = 0.f;
  int cnt = 0;
  int cur = batch[n0];
  for (int i = n0; i < n1; ++i) {
    int g = batch[i];
    if (g != cur) {
      atomicMax((int*)&gmax[cur * 128 + c], __float_as_int(mx));
      atomicAdd(&gsum[cur * 128 + c], sm);
      if (c == 0) atomicAdd(&gcnt[cur], (float)cnt);
      mx = 0.f; sm = 0.f; cnt = 0; cur = g;
    }
    float v = h[(size_t)i * 128 + c];
    mx = fmaxf(mx, v);
    sm += v;
    ++cnt;
  }
  atomicMax((int*)&gmax[cur * 128 + c], __float_as_int(mx));
  atomicAdd(&gsum[cur * 128 + c], sm);
  if (c == 0) atomicAdd(&gcnt[cur], (float)cnt);
}

// ---------------- MLP: one block per graph row ----------------

__global__ __launch_bounds__(128) void mlp_kernel(const float* __restrict__ gmax,
    const float* __restrict__ gsum, const float* __restrict__ gcnt,
    const float* __restrict__ rho,
    const float* __restrict__ w1, const float* __restrict__ b1,
    const float* __restrict__ w2, const float* __restrict__ b2,
    const float* __restrict__ w3, const float* __restrict__ b3,
    float* __restrict__ out) {
  __shared__ float s_in[257];
  __shared__ float s_z1[128];
  __shared__ float s_z2[128];
  int g = blockIdx.x, t = threadIdx.x;
  float inv_cnt = 1.f / fmaxf(gcnt[g], 1.f);
  s_in[t] = gmax[g * 128 + t];
  s_in[128 + t] = gsum[g * 128 + t] * inv_cnt;
  if (t == 0) s_in[256] = rho[g];
  __syncthreads();
  float s = b1[t];
  for (int k = 0; k < 257; ++k) s += s_in[k] * w1[k * 128 + t];
  s_z1[t] = relu_f(s);
  __syncthreads();
  s = b2[t];
  for (int k = 0; k < 128; ++k) s += s_z1[k] * w2[k * 128 + t];
  s_z2[t] = relu_f(s);
  __syncthreads();
  if (t < 36) {
    s = b3[t];
    for (int k = 0; k < 128; ++k) s += s_z2[k] * w3[k * 36 + t];
    out[g * 36 + t] = s;
  }
}

// ---------------- launch ----------------

extern "C" void kernel_launch(void* const* d_in, const int* in_sizes, int n_in,
                              void* d_out, int out_size, void* d_ws, size_t ws_size,
                              hipStream_t stream) {
  const float* x      = (const float*)d_in[0];
  const float* ew     = (const float*)d_in[1];
  const float* rho    = (const float*)d_in[2];
  const float* conv_w = (const float*)d_in[3];
  const float* conv_b = (const float*)d_in[4];
  const float* w1 = (const float*)d_in[5];
  const float* b1 = (const float*)d_in[6];
  const float* w2 = (const float*)d_in[7];
  const float* b2 = (const float*)d_in[8];
  const float* w3 = (const float*)d_in[9];
  const float* b3 = (const float*)d_in[10];
  const int* eidx  = (const int*)d_in[11];
  const int* batch = (const int*)d_in[12];

  const int N = in_sizes[0] / 128;
  const int E = in_sizes[1];
  const int G = in_sizes[2];
  const int* srcp = eidx;
  const int* dstp = eidx + E;

  const int NB = (N + 1023) / 1024;  // scan blocks (40 for N=40000)

  char* p = (char*)d_ws;
  auto carve = [&](size_t bytes) { char* r = p; p += (bytes + 255) & ~(size_t)255; return (void*)r; };
  float*   dinv   = (float*)  carve((size_t)N * 4);
  int*     indeg  = (int*)    carve((size_t)N * 4);
  int*     rowptr = (int*)    carve((size_t)(N + 1) * 4);
  int*     rank   = (int*)    carve((size_t)E * 4);
  int*     bsum   = (int*)    carve((size_t)NB * 4);
  int2*    epack  = (int2*)   carve((size_t)E * 8);
  __half2* xh     = (__half2*)carve((size_t)N * 128 * 2);
  float*   agg    = (float*)  carve((size_t)N * 128 * 4);  // reused in-place as h
  float*   gmax   = (float*)  carve((size_t)G * 128 * 4);
  float*   gsum   = (float*)  carve((size_t)G * 128 * 4);
  float*   gcnt   = (float*)  carve((size_t)G * 4);

  const int n4 = N * 32;  // float4 count of x

  init_kernel<<<(N + 255) / 256, 256, 0, stream>>>(indeg, gmax, gsum, gcnt, N, G * 128);
  cast_kernel<<<(n4 + 255) / 256, 256, 0, stream>>>((const float4*)x, xh, n4);
  count_rank_kernel<<<(E + 255) / 256, 256, 0, stream>>>(dstp, indeg, rank, E);
  scan_reduce_kernel<<<NB, 1024, 0, stream>>>(indeg, bsum, N);
  scan_bsum_kernel<<<1, 1024, 0, stream>>>(bsum, NB);
  scan_write_kernel<<<NB, 1024, 0, stream>>>(indeg, bsum, rowptr, N);
  edge_fill_kernel<<<(E + 255) / 256, 256, 0, stream>>>(srcp, dstp, ew, rank, rowptr, epack, E);
  row_dinv_kernel<<<(N + 255) / 256, 256, 0, stream>>>(rowptr, epack, dinv, N);
  aggregate_kernel<<<(N + 3) / 4, 256, 0, stream>>>((const float2*)x, xh, dinv, rowptr, epack,
                                                    (float2*)agg, N);
  gemm_relu_kernel<<<(N + 31) / 32, 256, 0, stream>>>((const float4*)agg, conv_w, conv_b,
                                                      (float4*)agg, N);
  pool_kernel<<<(N + POOL_CHUNK - 1) / POOL_CHUNK, 128, 0, stream>>>(agg, batch, gmax, gsum,
                                                                     gcnt, N);
  mlp_kernel<<<G, 128, 0, stream>>>(gmax, gsum, gcnt, rho, w1, b1, w2, b2, w3, b3,
                                    (float*)d_out);
}

// Round 7
// 238.007 us; speedup vs baseline: 2.3334x; 1.0456x over previous
//
#include <hip/hip_runtime.h>
#include <hip/hip_bf16.h>
#include <hip/hip_fp16.h>

static __device__ __forceinline__ float relu_f(float v) { return v > 0.f ? v : 0.f; }

// ---------------- fused init + fp16 cast of x ----------------

__global__ void cast_init_kernel(const float4* __restrict__ x4, __half2* __restrict__ xh2,
                                 int n4, int* __restrict__ indeg, int n,
                                 float* __restrict__ gmax, float* __restrict__ gsum,
                                 float* __restrict__ gcnt, int gch, int g) {
  int i = blockIdx.x * blockDim.x + threadIdx.x;
  if (i < n4) {
    float4 v = x4[i];
    xh2[2 * i + 0] = __floats2half2_rn(v.x, v.y);
    xh2[2 * i + 1] = __floats2half2_rn(v.z, v.w);
  }
  if (i < n) indeg[i] = 0;
  if (i < gch) { gmax[i] = 0.f; gsum[i] = 0.f; }
  if (i < g) gcnt[i] = 0.f;
}

// one atomic per edge; rank = within-bucket arrival order
__global__ void count_rank_kernel(const int* __restrict__ dst, int* __restrict__ indeg,
                                  int* __restrict__ rank, int E) {
  int e = blockIdx.x * blockDim.x + threadIdx.x;
  if (e >= E) return;
  rank[e] = atomicAdd(&indeg[dst[e]], 1);
}

// ---------------- device-wide exclusive scan of indeg (2 kernels) ----------------

__global__ __launch_bounds__(1024) void scan_reduce_kernel(const int* __restrict__ indeg,
                                                           int* __restrict__ bsum, int n) {
  int i = blockIdx.x * 1024 + threadIdx.x;
  int v = (i < n) ? indeg[i] : 0;
  #pragma unroll
  for (int off = 32; off; off >>= 1) v += __shfl_down(v, off, 64);
  __shared__ int ws[16];
  int lane = threadIdx.x & 63, wid = threadIdx.x >> 6;
  if (lane == 0) ws[wid] = v;
  __syncthreads();
  if (threadIdx.x == 0) {
    int s = 0;
    #pragma unroll
    for (int j = 0; j < 16; ++j) s += ws[j];
    bsum[blockIdx.x] = s;
  }
}

// each block computes its own bsum-prefix with one wave (nb small), then block-local scan
__global__ __launch_bounds__(1024) void scan_write_kernel(const int* __restrict__ indeg,
    const int* __restrict__ bsum, int* __restrict__ rowptr, int n, int nb) {
  int i = blockIdx.x * 1024 + threadIdx.x;
  int v = (i < n) ? indeg[i] : 0;
  int lane = threadIdx.x & 63, wid = threadIdx.x >> 6;
  int inc = v;
  #pragma unroll
  for (int off = 1; off < 64; off <<= 1) {
    int u = __shfl_up(inc, off, 64);
    if (lane >= off) inc += u;
  }
  __shared__ int wtot[16];
  __shared__ int s_off;
  if (lane == 63) wtot[wid] = inc;
  if (threadIdx.x < 64) {
    int acc = 0;
    for (int base = 0; base < nb; base += 64) {
      int idx = base + (int)threadIdx.x;
      int val = (idx < nb && idx < (int)blockIdx.x) ? bsum[idx] : 0;
      #pragma unroll
      for (int off = 32; off; off >>= 1) val += __shfl_down(val, off, 64);
      if (threadIdx.x == 0) acc += val;
    }
    if (threadIdx.x == 0) s_off = acc;
  }
  __syncthreads();
  int woff = 0;
  for (int j = 0; j < wid; ++j) woff += wtot[j];
  int excl = s_off + woff + inc - v;
  if (i < n) {
    rowptr[i + 1] = excl + v;
    if (i == 0) rowptr[0] = 0;
  }
}

// no atomics: slot = rowptr[dst] + rank
__global__ void edge_fill_kernel(const int* __restrict__ src, const int* __restrict__ dst,
                                 const float* __restrict__ ew, const int* __restrict__ rank,
                                 const int* __restrict__ rowptr, int2* __restrict__ epack,
                                 int E) {
  int e = blockIdx.x * blockDim.x + threadIdx.x;
  if (e >= E) return;
  int d = dst[e];
  int slot = rowptr[d] + rank[e];
  epack[slot] = make_int2(src[e], __float_as_int(ew[e]));
}

// deg[i] = 1 + sum of ew over row i (contiguous read); dinv = rsqrt
__global__ void row_dinv_kernel(const int* __restrict__ rowptr, const int2* __restrict__ epack,
                                float* __restrict__ dinv, int n) {
  int i = blockIdx.x * blockDim.x + threadIdx.x;
  if (i >= n) return;
  int s = rowptr[i], e = rowptr[i + 1];
  float d = 1.0f;  // self-loop weight
  for (int j = s; j < e; ++j) d += __int_as_float(epack[j].y);
  dinv[i] = (d > 0.f) ? rsqrtf(d) : 0.f;
}

// ---------------- aggregation: one wave per node, fp16 gathers, 8 in flight ----------------

__global__ __launch_bounds__(256) void aggregate_kernel(const float2* __restrict__ x2,
    const __half2* __restrict__ xh2,
    const float* __restrict__ dinv, const int* __restrict__ rowptr,
    const int2* __restrict__ epack, float2* __restrict__ agg2, int n) {
  int gid = blockIdx.x * blockDim.x + threadIdx.x;
  int node = gid >> 6;
  int lane = gid & 63;
  if (node >= n) return;
  float dn = dinv[node];
  float2 xv = x2[node * 64 + lane];
  float sw = dn * dn;  // self-loop norm
  float2 acc = make_float2(sw * xv.x, sw * xv.y);
  int s = rowptr[node], e = rowptr[node + 1];
  int j = s;
  for (; j + 8 <= e; j += 8) {
    int2 pk[8];
    #pragma unroll
    for (int u = 0; u < 8; ++u) pk[u] = epack[j + u];
    __half2 hx[8];
    float dw[8];
    #pragma unroll
    for (int u = 0; u < 8; ++u) {
      hx[u] = xh2[(size_t)pk[u].x * 64 + lane];
      dw[u] = dinv[pk[u].x];
    }
    #pragma unroll
    for (int u = 0; u < 8; ++u) {
      float w = dw[u] * __int_as_float(pk[u].y) * dn;
      float2 xc = __half22float2(hx[u]);
      acc.x += w * xc.x;
      acc.y += w * xc.y;
    }
  }
  for (; j < e; ++j) {
    int2 pk = epack[j];
    float w = dinv[pk.x] * __int_as_float(pk.y) * dn;
    float2 xc = __half22float2(xh2[(size_t)pk.x * 64 + lane]);
    acc.x += w * xc.x;
    acc.y += w * xc.y;
  }
  agg2[node * 64 + lane] = acc;
}

// ---------------- fused GEMM (agg @ W + b, ReLU) + pooling, 32 rows/block ----------------
// h is never materialized: the 32-row post-ReLU tile is pooled from LDS.
// batch is sorted -> a 16-row half spans few segments; per-segment register
// accumulate then one atomic flush per (segment, channel).

__global__ __launch_bounds__(256) void gemm_pool_kernel(const float4* __restrict__ agg4,
    const float* __restrict__ W, const float* __restrict__ bias,
    const int* __restrict__ batch, float* __restrict__ gmax, float* __restrict__ gsum,
    float* __restrict__ gcnt, int n) {
  __shared__ float sA[32 * 128];   // 16 KB (A tile, then reused for h tile)
  __shared__ float sW[64 * 128];   // 32 KB (two K-chunks)
  __shared__ int sBatch[32];
  int tid = threadIdx.x;
  int row0 = blockIdx.x * 32;
  int nb = n - row0; if (nb > 32) nb = 32;
  float4* sA4 = (float4*)sA;
  for (int idx = tid; idx < 32 * 32; idx += 256) {
    int r = idx >> 5;
    sA4[idx] = (r < nb) ? agg4[(size_t)row0 * 32 + idx] : make_float4(0.f, 0.f, 0.f, 0.f);
  }
  int tx = tid & 31, ty = tid >> 5;   // cols 4*tx..+3, rows 4*ty..+3
  float acc[4][4] = {};
  const float4* W4 = (const float4*)W;
  float4* sW4 = (float4*)sW;
  for (int kk = 0; kk < 128; kk += 64) {
    __syncthreads();
    for (int idx = tid; idx < 64 * 32; idx += 256)
      sW4[idx] = W4[kk * 32 + idx];
    __syncthreads();
    #pragma unroll 8
    for (int k = 0; k < 64; ++k) {
      float a0 = sA[(4 * ty + 0) * 128 + kk + k];
      float a1 = sA[(4 * ty + 1) * 128 + kk + k];
      float a2 = sA[(4 * ty + 2) * 128 + kk + k];
      float a3 = sA[(4 * ty + 3) * 128 + kk + k];
      float4 wv = *(const float4*)&sW[k * 128 + 4 * tx];
      acc[0][0] += a0 * wv.x; acc[0][1] += a0 * wv.y; acc[0][2] += a0 * wv.z; acc[0][3] += a0 * wv.w;
      acc[1][0] += a1 * wv.x; acc[1][1] += a1 * wv.y; acc[1][2] += a1 * wv.z; acc[1][3] += a1 * wv.w;
      acc[2][0] += a2 * wv.x; acc[2][1] += a2 * wv.y; acc[2][2] += a2 * wv.z; acc[2][3] += a2 * wv.w;
      acc[3][0] += a3 * wv.x; acc[3][1] += a3 * wv.y; acc[3][2] += a3 * wv.z; acc[3][3] += a3 * wv.w;
    }
  }
  __syncthreads();  // all sA reads done before overwrite
  float4 bb = ((const float4*)bias)[tx];
  #pragma unroll
  for (int i = 0; i < 4; ++i) {
    int r = 4 * ty + i;
    if (r < nb) {
      float4 o;
      o.x = relu_f(acc[i][0] + bb.x);
      o.y = relu_f(acc[i][1] + bb.y);
      o.z = relu_f(acc[i][2] + bb.z);
      o.w = relu_f(acc[i][3] + bb.w);
      *(float4*)&sA[r * 128 + 4 * tx] = o;
    }
  }
  if (tid < 32 && tid < nb) sBatch[tid] = batch[row0 + tid];
  __syncthreads();
  // pooling: two halves of 16 rows; c = channel
  int half = tid >> 7, c = tid & 127;
  int r0 = half * 16, r1 = r0 + 16;
  if (r1 > nb) r1 = nb;
  if (r0 < r1) {
    int cur = sBatch[r0];
    float mx = 0.f, sm = 0.f;
    int cnt = 0;
    for (int r = r0; r < r1; ++r) {
      int g = sBatch[r];
      if (g != cur) {
        atomicMax((int*)&gmax[cur * 128 + c], __float_as_int(mx));
        atomicAdd(&gsum[cur * 128 + c], sm);
        if (c == 0) atomicAdd(&gcnt[cur], (float)cnt);
        mx = 0.f; sm = 0.f; cnt = 0; cur = g;
      }
      float v = sA[r * 128 + c];
      mx = fmaxf(mx, v);
      sm += v;
      ++cnt;
    }
    atomicMax((int*)&gmax[cur * 128 + c], __float_as_int(mx));
    atomicAdd(&gsum[cur * 128 + c], sm);
    if (c == 0) atomicAdd(&gcnt[cur], (float)cnt);
  }
}

// ---------------- MLP: one block per graph row ----------------

__global__ __launch_bounds__(128) void mlp_kernel(const float* __restrict__ gmax,
    const float* __restrict__ gsum, const float* __restrict__ gcnt,
    const float* __restrict__ rho,
    const float* __restrict__ w1, const float* __restrict__ b1,
    const float* __restrict__ w2, const float* __restrict__ b2,
    const float* __restrict__ w3, const float* __restrict__ b3,
    float* __restrict__ out) {
  __shared__ float s_in[257];
  __shared__ float s_z1[128];
  __shared__ float s_z2[128];
  int g = blockIdx.x, t = threadIdx.x;
  float inv_cnt = 1.f / fmaxf(gcnt[g], 1.f);
  s_in[t] = gmax[g * 128 + t];
  s_in[128 + t] = gsum[g * 128 + t] * inv_cnt;
  if (t == 0) s_in[256] = rho[g];
  __syncthreads();
  float s = b1[t];
  for (int k = 0; k < 257; ++k) s += s_in[k] * w1[k * 128 + t];
  s_z1[t] = relu_f(s);
  __syncthreads();
  s = b2[t];
  for (int k = 0; k < 128; ++k) s += s_z1[k] * w2[k * 128 + t];
  s_z2[t] = relu_f(s);
  __syncthreads();
  if (t < 36) {
    s = b3[t];
    for (int k = 0; k < 128; ++k) s += s_z2[k] * w3[k * 36 + t];
    out[g * 36 + t] = s;
  }
}

// ---------------- launch ----------------

extern "C" void kernel_launch(void* const* d_in, const int* in_sizes, int n_in,
                              void* d_out, int out_size, void* d_ws, size_t ws_size,
                              hipStream_t stream) {
  const float* x      = (const float*)d_in[0];
  const float* ew     = (const float*)d_in[1];
  const float* rho    = (const float*)d_in[2];
  const float* conv_w = (const float*)d_in[3];
  const float* conv_b = (const float*)d_in[4];
  const float* w1 = (const float*)d_in[5];
  const float* b1 = (const float*)d_in[6];
  const float* w2 = (const float*)d_in[7];
  const float* b2 = (const float*)d_in[8];
  const float* w3 = (const float*)d_in[9];
  const float* b3 = (const float*)d_in[10];
  const int* eidx  = (const int*)d_in[11];
  const int* batch = (const int*)d_in[12];

  const int N = in_sizes[0] / 128;
  const int E = in_sizes[1];
  const int G = in_sizes[2];
  const int* srcp = eidx;
  const int* dstp = eidx + E;

  const int NB = (N + 1023) / 1024;  // scan blocks (40 for N=40000)

  char* p = (char*)d_ws;
  auto carve = [&](size_t bytes) { char* r = p; p += (bytes + 255) & ~(size_t)255; return (void*)r; };
  float*   dinv   = (float*)  carve((size_t)N * 4);
  int*     indeg  = (int*)    carve((size_t)N * 4);
  int*     rowptr = (int*)    carve((size_t)(N + 1) * 4);
  int*     rank   = (int*)    carve((size_t)E * 4);
  int*     bsum   = (int*)    carve((size_t)NB * 4);
  int2*    epack  = (int2*)   carve((size_t)E * 8);
  __half2* xh     = (__half2*)carve((size_t)N * 128 * 2);
  float*   agg    = (float*)  carve((size_t)N * 128 * 4);
  float*   gmax   = (float*)  carve((size_t)G * 128 * 4);
  float*   gsum   = (float*)  carve((size_t)G * 128 * 4);
  float*   gcnt   = (float*)  carve((size_t)G * 4);

  const int n4 = N * 32;  // float4 count of x

  cast_init_kernel<<<(n4 + 255) / 256, 256, 0, stream>>>((const float4*)x, xh, n4,
                                                         indeg, N, gmax, gsum, gcnt,
                                                         G * 128, G);
  count_rank_kernel<<<(E + 255) / 256, 256, 0, stream>>>(dstp, indeg, rank, E);
  scan_reduce_kernel<<<NB, 1024, 0, stream>>>(indeg, bsum, N);
  scan_write_kernel<<<NB, 1024, 0, stream>>>(indeg, bsum, rowptr, N, NB);
  edge_fill_kernel<<<(E + 255) / 256, 256, 0, stream>>>(srcp, dstp, ew, rank, rowptr, epack, E);
  row_dinv_kernel<<<(N + 255) / 256, 256, 0, stream>>>(rowptr, epack, dinv, N);
  aggregate_kernel<<<(N + 3) / 4, 256, 0, stream>>>((const float2*)x, xh, dinv, rowptr, epack,
                                                    (float2*)agg, N);
  gemm_pool_kernel<<<(N + 31) / 32, 256, 0, stream>>>((const float4*)agg, conv_w, conv_b,
                                                      batch, gmax, gsum, gcnt, N);
  mlp_kernel<<<G, 128, 0, stream>>>(gmax, gsum, gcnt, rho, w1, b1, w2, b2, w3, b3,
                                    (float*)d_out);
}

// Round 8
// 222.591 us; speedup vs baseline: 2.4950x; 1.0693x over previous
//
#include <hip/hip_runtime.h>
#include <hip/hip_bf16.h>
#include <hip/hip_fp16.h>

static __device__ __forceinline__ float relu_f(float v) { return v > 0.f ? v : 0.f; }

typedef _Float16 half8 __attribute__((ext_vector_type(8)));
typedef float floatx4 __attribute__((ext_vector_type(4)));

// ---------------- fused init + fp16 cast of x ----------------

__global__ void cast_init_kernel(const float4* __restrict__ x4, __half2* __restrict__ xh2,
                                 int n4, int* __restrict__ indeg, int n,
                                 float* __restrict__ gmax, float* __restrict__ gsum,
                                 float* __restrict__ gcnt, int gch, int g) {
  int i = blockIdx.x * blockDim.x + threadIdx.x;
  if (i < n4) {
    float4 v = x4[i];
    xh2[2 * i + 0] = __floats2half2_rn(v.x, v.y);
    xh2[2 * i + 1] = __floats2half2_rn(v.z, v.w);
  }
  if (i < n) indeg[i] = 0;
  if (i < gch) { gmax[i] = 0.f; gsum[i] = 0.f; }
  if (i < g) gcnt[i] = 0.f;
}

// W (f32 [k][n]) -> Wt (fp16 [n][k]) for MFMA B-fragment vector loads
__global__ void wt_cast_kernel(const float* __restrict__ W, _Float16* __restrict__ wt) {
  int idx = blockIdx.x * blockDim.x + threadIdx.x;  // 0..16383
  int k = idx >> 7, nn = idx & 127;
  wt[nn * 128 + k] = (_Float16)W[idx];
}

// one atomic per edge; rank = within-bucket arrival order
__global__ void count_rank_kernel(const int* __restrict__ dst, int* __restrict__ indeg,
                                  int* __restrict__ rank, int E) {
  int e = blockIdx.x * blockDim.x + threadIdx.x;
  if (e >= E) return;
  rank[e] = atomicAdd(&indeg[dst[e]], 1);
}

// ---------------- device-wide exclusive scan of indeg (2 kernels) ----------------

__global__ __launch_bounds__(1024) void scan_reduce_kernel(const int* __restrict__ indeg,
                                                           int* __restrict__ bsum, int n) {
  int i = blockIdx.x * 1024 + threadIdx.x;
  int v = (i < n) ? indeg[i] : 0;
  #pragma unroll
  for (int off = 32; off; off >>= 1) v += __shfl_down(v, off, 64);
  __shared__ int ws[16];
  int lane = threadIdx.x & 63, wid = threadIdx.x >> 6;
  if (lane == 0) ws[wid] = v;
  __syncthreads();
  if (threadIdx.x == 0) {
    int s = 0;
    #pragma unroll
    for (int j = 0; j < 16; ++j) s += ws[j];
    bsum[blockIdx.x] = s;
  }
}

__global__ __launch_bounds__(1024) void scan_write_kernel(const int* __restrict__ indeg,
    const int* __restrict__ bsum, int* __restrict__ rowptr, int n, int nb) {
  int i = blockIdx.x * 1024 + threadIdx.x;
  int v = (i < n) ? indeg[i] : 0;
  int lane = threadIdx.x & 63, wid = threadIdx.x >> 6;
  int inc = v;
  #pragma unroll
  for (int off = 1; off < 64; off <<= 1) {
    int u = __shfl_up(inc, off, 64);
    if (lane >= off) inc += u;
  }
  __shared__ int wtot[16];
  __shared__ int s_off;
  if (lane == 63) wtot[wid] = inc;
  if (threadIdx.x < 64) {
    int acc = 0;
    for (int base = 0; base < nb; base += 64) {
      int idx = base + (int)threadIdx.x;
      int val = (idx < nb && idx < (int)blockIdx.x) ? bsum[idx] : 0;
      #pragma unroll
      for (int off = 32; off; off >>= 1) val += __shfl_down(val, off, 64);
      if (threadIdx.x == 0) acc += val;
    }
    if (threadIdx.x == 0) s_off = acc;
  }
  __syncthreads();
  int woff = 0;
  for (int j = 0; j < wid; ++j) woff += wtot[j];
  int excl = s_off + woff + inc - v;
  if (i < n) {
    rowptr[i + 1] = excl + v;
    if (i == 0) rowptr[0] = 0;
  }
}

// no atomics: slot = rowptr[dst] + rank
__global__ void edge_fill_kernel(const int* __restrict__ src, const int* __restrict__ dst,
                                 const float* __restrict__ ew, const int* __restrict__ rank,
                                 const int* __restrict__ rowptr, int2* __restrict__ epack,
                                 int E) {
  int e = blockIdx.x * blockDim.x + threadIdx.x;
  if (e >= E) return;
  int d = dst[e];
  int slot = rowptr[d] + rank[e];
  epack[slot] = make_int2(src[e], __float_as_int(ew[e]));
}

// deg[i] = 1 + sum of ew over row i (contiguous read); dinv = rsqrt
__global__ void row_dinv_kernel(const int* __restrict__ rowptr, const int2* __restrict__ epack,
                                float* __restrict__ dinv, int n) {
  int i = blockIdx.x * blockDim.x + threadIdx.x;
  if (i >= n) return;
  int s = rowptr[i], e = rowptr[i + 1];
  float d = 1.0f;  // self-loop weight
  for (int j = s; j < e; ++j) d += __int_as_float(epack[j].y);
  dinv[i] = (d > 0.f) ? rsqrtf(d) : 0.f;
}

// ---------------- aggregation: one wave per node, fp16 gathers, fp16 output ----------------

__global__ __launch_bounds__(256) void aggregate_kernel(const __half2* __restrict__ xh2,
    const float* __restrict__ dinv, const int* __restrict__ rowptr,
    const int2* __restrict__ epack, __half2* __restrict__ aggh2, int n) {
  int gid = blockIdx.x * blockDim.x + threadIdx.x;
  int node = gid >> 6;
  int lane = gid & 63;
  if (node >= n) return;
  float dn = dinv[node];
  float2 xv = __half22float2(xh2[node * 64 + lane]);
  float sw = dn * dn;  // self-loop norm
  float2 acc = make_float2(sw * xv.x, sw * xv.y);
  int s = rowptr[node], e = rowptr[node + 1];
  int j = s;
  for (; j + 8 <= e; j += 8) {
    int2 pk[8];
    #pragma unroll
    for (int u = 0; u < 8; ++u) pk[u] = epack[j + u];
    __half2 hx[8];
    float dw[8];
    #pragma unroll
    for (int u = 0; u < 8; ++u) {
      hx[u] = xh2[(size_t)pk[u].x * 64 + lane];
      dw[u] = dinv[pk[u].x];
    }
    #pragma unroll
    for (int u = 0; u < 8; ++u) {
      float w = dw[u] * __int_as_float(pk[u].y) * dn;
      float2 xc = __half22float2(hx[u]);
      acc.x += w * xc.x;
      acc.y += w * xc.y;
    }
  }
  for (; j < e; ++j) {
    int2 pk = epack[j];
    float w = dinv[pk.x] * __int_as_float(pk.y) * dn;
    float2 xc = __half22float2(xh2[(size_t)pk.x * 64 + lane]);
    acc.x += w * xc.x;
    acc.y += w * xc.y;
  }
  aggh2[node * 64 + lane] = __floats2half2_rn(acc.x, acc.y);
}

// ---------------- fused MFMA GEMM (aggh @ W + b, ReLU) + pooling ----------------
// 64 rows/block, 4 waves; wave w owns rows [w*16, w*16+16).
// A/B fragments loaded directly from global (L2-resident, 64B segments).
// mfma_f32_16x16x32_f16: A[m=lane&15][k=quad*8+j]; B[k=quad*8+j][n=lane&15]
// (B from Wt[n][k] so the 8 k-values are contiguous); D: col=lane&15,
// row=quad*4+reg. Epilogue: relu(acc+bias) -> LDS h[64][129] -> segment pool.

__global__ __launch_bounds__(256) void gemm_pool_kernel(const _Float16* __restrict__ aggh,
    const _Float16* __restrict__ wt, const float* __restrict__ bias,
    const int* __restrict__ batch, float* __restrict__ gmax, float* __restrict__ gsum,
    float* __restrict__ gcnt, int n) {
  __shared__ float sH[64 * 129];
  __shared__ int sBatch[64];
  int tid = threadIdx.x;
  int w = tid >> 6, lane = tid & 63;
  int quad = lane >> 4, c15 = lane & 15;
  int row0 = blockIdx.x * 64;
  int nb = n - row0; if (nb > 64) nb = 64;

  float bb[8];
  #pragma unroll
  for (int j = 0; j < 8; ++j) bb[j] = bias[j * 16 + c15];

  int arow = row0 + w * 16 + c15;
  if (arow >= n) arow = n - 1;  // clamped rows are discarded by the nb guard
  const half8* aptr = (const half8*)(aggh + (size_t)arow * 128 + quad * 8);

  floatx4 acc[8] = {};
  #pragma unroll
  for (int ks = 0; ks < 4; ++ks) {
    half8 af = aptr[ks * 4];  // +32 halves per k-step
    #pragma unroll
    for (int j = 0; j < 8; ++j) {
      const half8* bptr =
          (const half8*)(wt + (size_t)(j * 16 + c15) * 128 + ks * 32 + quad * 8);
      acc[j] = __builtin_amdgcn_mfma_f32_16x16x32_f16(af, *bptr, acc[j], 0, 0, 0);
    }
  }

  if (tid < nb) sBatch[tid] = batch[row0 + tid];

  #pragma unroll
  for (int j = 0; j < 8; ++j) {
    int col = j * 16 + c15;
    #pragma unroll
    for (int r = 0; r < 4; ++r) {
      int row = w * 16 + quad * 4 + r;
      if (row < nb) sH[row * 129 + col] = relu_f(acc[j][r] + bb[j]);
    }
  }
  __syncthreads();

  int c = tid & 127, hf = tid >> 7;
  int r0 = hf * 32, r1 = r0 + 32;
  if (r1 > nb) r1 = nb;
  if (r0 < r1) {
    int cur = sBatch[r0];
    float mx = 0.f, sm = 0.f;
    int cnt = 0;
    for (int r = r0; r < r1; ++r) {
      int g = sBatch[r];
      if (g != cur) {
        atomicMax((int*)&gmax[cur * 128 + c], __float_as_int(mx));
        atomicAdd(&gsum[cur * 128 + c], sm);
        if (c == 0) atomicAdd(&gcnt[cur], (float)cnt);
        mx = 0.f; sm = 0.f; cnt = 0; cur = g;
      }
      float v = sH[r * 129 + c];
      mx = fmaxf(mx, v);
      sm += v;
      ++cnt;
    }
    atomicMax((int*)&gmax[cur * 128 + c], __float_as_int(mx));
    atomicAdd(&gsum[cur * 128 + c], sm);
    if (c == 0) atomicAdd(&gcnt[cur], (float)cnt);
  }
}

// ---------------- MLP: one block per graph row ----------------

__global__ __launch_bounds__(128) void mlp_kernel(const float* __restrict__ gmax,
    const float* __restrict__ gsum, const float* __restrict__ gcnt,
    const float* __restrict__ rho,
    const float* __restrict__ w1, const float* __restrict__ b1,
    const float* __restrict__ w2, const float* __restrict__ b2,
    const float* __restrict__ w3, const float* __restrict__ b3,
    float* __restrict__ out) {
  __shared__ float s_in[257];
  __shared__ float s_z1[128];
  __shared__ float s_z2[128];
  int g = blockIdx.x, t = threadIdx.x;
  float inv_cnt = 1.f / fmaxf(gcnt[g], 1.f);
  s_in[t] = gmax[g * 128 + t];
  s_in[128 + t] = gsum[g * 128 + t] * inv_cnt;
  if (t == 0) s_in[256] = rho[g];
  __syncthreads();
  float s = b1[t];
  for (int k = 0; k < 257; ++k) s += s_in[k] * w1[k * 128 + t];
  s_z1[t] = relu_f(s);
  __syncthreads();
  s = b2[t];
  for (int k = 0; k < 128; ++k) s += s_z1[k] * w2[k * 128 + t];
  s_z2[t] = relu_f(s);
  __syncthreads();
  if (t < 36) {
    s = b3[t];
    for (int k = 0; k < 128; ++k) s += s_z2[k] * w3[k * 36 + t];
    out[g * 36 + t] = s;
  }
}

// ---------------- launch ----------------

extern "C" void kernel_launch(void* const* d_in, const int* in_sizes, int n_in,
                              void* d_out, int out_size, void* d_ws, size_t ws_size,
                              hipStream_t stream) {
  const float* x      = (const float*)d_in[0];
  const float* ew     = (const float*)d_in[1];
  const float* rho    = (const float*)d_in[2];
  const float* conv_w = (const float*)d_in[3];
  const float* conv_b = (const float*)d_in[4];
  const float* w1 = (const float*)d_in[5];
  const float* b1 = (const float*)d_in[6];
  const float* w2 = (const float*)d_in[7];
  const float* b2 = (const float*)d_in[8];
  const float* w3 = (const float*)d_in[9];
  const float* b3 = (const float*)d_in[10];
  const int* eidx  = (const int*)d_in[11];
  const int* batch = (const int*)d_in[12];

  const int N = in_sizes[0] / 128;
  const int E = in_sizes[1];
  const int G = in_sizes[2];
  const int* srcp = eidx;
  const int* dstp = eidx + E;

  const int NB = (N + 1023) / 1024;  // scan blocks (40 for N=40000)

  char* p = (char*)d_ws;
  auto carve = [&](size_t bytes) { char* r = p; p += (bytes + 255) & ~(size_t)255; return (void*)r; };
  float*    dinv   = (float*)   carve((size_t)N * 4);
  int*      indeg  = (int*)     carve((size_t)N * 4);
  int*      rowptr = (int*)     carve((size_t)(N + 1) * 4);
  int*      rank   = (int*)     carve((size_t)E * 4);
  int*      bsum   = (int*)     carve((size_t)NB * 4);
  int2*     epack  = (int2*)    carve((size_t)E * 8);
  __half2*  xh     = (__half2*) carve((size_t)N * 128 * 2);
  _Float16* aggh   = (_Float16*)carve((size_t)N * 128 * 2);
  _Float16* wt     = (_Float16*)carve((size_t)128 * 128 * 2);
  float*    gmax   = (float*)   carve((size_t)G * 128 * 4);
  float*    gsum   = (float*)   carve((size_t)G * 128 * 4);
  float*    gcnt   = (float*)   carve((size_t)G * 4);

  const int n4 = N * 32;  // float4 count of x

  cast_init_kernel<<<(n4 + 255) / 256, 256, 0, stream>>>((const float4*)x, xh, n4,
                                                         indeg, N, gmax, gsum, gcnt,
                                                         G * 128, G);
  wt_cast_kernel<<<64, 256, 0, stream>>>(conv_w, wt);
  count_rank_kernel<<<(E + 255) / 256, 256, 0, stream>>>(dstp, indeg, rank, E);
  scan_reduce_kernel<<<NB, 1024, 0, stream>>>(indeg, bsum, N);
  scan_write_kernel<<<NB, 1024, 0, stream>>>(indeg, bsum, rowptr, N, NB);
  edge_fill_kernel<<<(E + 255) / 256, 256, 0, stream>>>(srcp, dstp, ew, rank, rowptr, epack, E);
  row_dinv_kernel<<<(N + 255) / 256, 256, 0, stream>>>(rowptr, epack, dinv, N);
  aggregate_kernel<<<(N + 3) / 4, 256, 0, stream>>>(xh, dinv, rowptr, epack,
                                                    (__half2*)aggh, N);
  gemm_pool_kernel<<<(N + 63) / 64, 256, 0, stream>>>(aggh, wt, conv_b, batch,
                                                      gmax, gsum, gcnt, N);
  mlp_kernel<<<G, 128, 0, stream>>>(gmax, gsum, gcnt, rho, w1, b1, w2, b2, w3, b3,
                                    (float*)d_out);
}